// Round 9
// baseline (181.235 us; speedup 1.0000x reference)
//
#include <hip/hip_runtime.h>
#include <cstdint>

#define Bv  2
#define Tv  2048
#define Dv  1024
#define Hv  16
#define DHv 64
#define Pv  512
#define Lv  2560   // P + T

typedef __attribute__((ext_vector_type(8))) short sh8;   // 8 bf16 MFMA frag
typedef __attribute__((ext_vector_type(4))) short sh4;
typedef __attribute__((ext_vector_type(4))) float f4;
typedef __attribute__((ext_vector_type(4))) unsigned int u4v;

#define MFMA(a,b,c) __builtin_amdgcn_mfma_f32_16x16x32_bf16(a,b,c,0,0,0)

__device__ __forceinline__ unsigned short bf16_rn(float f) {
    unsigned int u = __builtin_bit_cast(unsigned int, f);
    u += 0x7FFFu + ((u >> 16) & 1u);          // RTNE
    return (unsigned short)(u >> 16);
}
__device__ __forceinline__ float bf16_f(unsigned short h) {
    unsigned int u = ((unsigned int)h) << 16;
    return __builtin_bit_cast(float, u);
}
__device__ __forceinline__ unsigned int fbits(float f) {
    return __builtin_bit_cast(unsigned int, f);
}

// async global->LDS, 16B per lane; LDS dest = wave-uniform base + lane*16
__device__ __forceinline__ void gload16(const unsigned short* g, unsigned short* l) {
    __builtin_amdgcn_global_load_lds(
        (const __attribute__((address_space(1))) unsigned int*)(g),
        (__attribute__((address_space(3))) unsigned int*)(l),
        16, 0, 0);
}

// exp2 + truncate-pack two QK accumulators (8 P values) into one bf16 B-frag.
__device__ __forceinline__ sh8 packP(const f4 a, const f4 b) {
    float e0 = __builtin_amdgcn_exp2f(a[0]), e1 = __builtin_amdgcn_exp2f(a[1]);
    float e2 = __builtin_amdgcn_exp2f(a[2]), e3 = __builtin_amdgcn_exp2f(a[3]);
    float f0 = __builtin_amdgcn_exp2f(b[0]), f1 = __builtin_amdgcn_exp2f(b[1]);
    float f2 = __builtin_amdgcn_exp2f(b[2]), f3 = __builtin_amdgcn_exp2f(b[3]);
    u4v d;
    d[0] = __builtin_amdgcn_perm(fbits(e1), fbits(e0), 0x07060302u);
    d[1] = __builtin_amdgcn_perm(fbits(e3), fbits(e2), 0x07060302u);
    d[2] = __builtin_amdgcn_perm(fbits(f1), fbits(f0), 0x07060302u);
    d[3] = __builtin_amdgcn_perm(fbits(f3), fbits(f2), 0x07060302u);
    return __builtin_bit_cast(sh8, d);
}

// ---------------------------------------------------------------------------
// Prep 1: fp32 -> bf16 conversions (x, Wq, Wk, Wv, pk single; Wo -> hi/lo).
// ---------------------------------------------------------------------------
__global__ __launch_bounds__(256) void prep_convert(
    const float* __restrict__ x,  const float* __restrict__ Wq,
    const float* __restrict__ Wk, const float* __restrict__ Wv,
    const float* __restrict__ pk, const float* __restrict__ Wo,
    unsigned short* __restrict__ xb,  unsigned short* __restrict__ wqb,
    unsigned short* __restrict__ wkb, unsigned short* __restrict__ wvb,
    unsigned short* __restrict__ pkb, unsigned short* __restrict__ woh,
    unsigned short* __restrict__ wol)
{
    int i = blockIdx.x * 256 + threadIdx.x;   // float4 index, total 2359296
    const float* src; unsigned short* dst; int off; bool split = false;
    if      (i < 1048576) { src = x;  dst = xb;  off = i; }
    else if (i < 1310720) { src = Wq; dst = wqb; off = i - 1048576; }
    else if (i < 1572864) { src = Wk; dst = wkb; off = i - 1310720; }
    else if (i < 1835008) { src = Wv; dst = wvb; off = i - 1572864; }
    else if (i < 2097152) { src = pk; dst = pkb; off = i - 1835008; }
    else                  { src = Wo; dst = woh; off = i - 2097152; split = true; }
    float4 v = reinterpret_cast<const float4*>(src)[off];
    float vv[4] = {v.x, v.y, v.z, v.w};
    sh4 h, l;
    #pragma unroll
    for (int j = 0; j < 4; j++) {
        unsigned short hh = bf16_rn(vv[j]);
        h[j] = (short)hh;
        l[j] = (short)bf16_rn(vv[j] - bf16_f(hh));
    }
    reinterpret_cast<sh4*>(dst)[off] = h;
    if (split) reinterpret_cast<sh4*>(wol)[off] = l;
}

// ---------------------------------------------------------------------------
// Prep 2: pv [B,H,P,DH] fp32 -> pvtb [B,H,DH,P'] bf16, keys tau-permuted
// within each 64-tile.  For run u (keys 8u+j):
// slot(j<4) = 32*((u>>2)&1) + 16*(u&1) + 4*((u>>1)&1) + j, slot(j>=4) = +8.
// ---------------------------------------------------------------------------
__global__ __launch_bounds__(256) void prep_transpose(
    const float* __restrict__ pv, unsigned short* __restrict__ pvtb)
{
    __shared__ unsigned short Tls[64][66];
    const int tid = threadIdx.x;
    const int bh = blockIdx.x >> 3, pt = blockIdx.x & 7;
    #pragma unroll
    for (int i = 0; i < 4; i++) {
        int id = i * 256 + tid;
        int p = id >> 4, c4 = (id & 15) << 2;
        float4 v = *reinterpret_cast<const float4*>(
            &pv[((size_t)bh * Pv + pt * 64 + p) * DHv + c4]);
        Tls[c4+0][p] = bf16_rn(v.x);
        Tls[c4+1][p] = bf16_rn(v.y);
        Tls[c4+2][p] = bf16_rn(v.z);
        Tls[c4+3][p] = bf16_rn(v.w);
    }
    __syncthreads();
    #pragma unroll
    for (int i = 0; i < 2; i++) {
        int id = i * 256 + tid;
        int d = id >> 3, u = id & 7;             // dh row, 8-key run index
        sh4 lo, hi;
        #pragma unroll
        for (int j = 0; j < 4; j++) {
            lo[j] = (short)Tls[d][u * 8 + j];
            hi[j] = (short)Tls[d][u * 8 + 4 + j];
        }
        int p0 = ((u >> 2) & 1) * 32 + (u & 1) * 16 + ((u >> 1) & 1) * 4;
        size_t base = ((size_t)bh * DHv + d) * Pv + pt * 64;
        *reinterpret_cast<sh4*>(&pvtb[base + p0])     = lo;
        *reinterpret_cast<sh4*>(&pvtb[base + p0 + 8]) = hi;
    }
}

// ---------------------------------------------------------------------------
// Kernel 1: QKV projection, single-bf16 MFMA, m97 structure (single-buffered).
// Q pre-scaled by 0.125*log2(e); V^T stored tau-permuted per 64-tile.
// 2-D grid (reverted: 1-D XCD clustering regressed ~5us in round 8).
// ---------------------------------------------------------------------------
__global__ __launch_bounds__(256) void qkv_gemm(
    const unsigned short* __restrict__ xb,
    const unsigned short* __restrict__ wqb, const unsigned short* __restrict__ wkb,
    const unsigned short* __restrict__ wvb,
    unsigned short* __restrict__ qb, unsigned short* __restrict__ kb,
    unsigned short* __restrict__ vtb)
{
    __shared__ __align__(16) unsigned short As[128 * 64], Bs[128 * 64];
    const int tid = threadIdx.x;
    const int lane = tid & 63, w = tid >> 6;
    const int g = lane >> 4, tx = lane & 15;
    const int wr = w >> 1, wc = w & 1;
    const int m0 = blockIdx.x * 128, n0 = blockIdx.y * 128;
    const int z = blockIdx.z;
    const unsigned short* Wb = (z == 0) ? wqb : (z == 1) ? wkb : wvb;
    const int srow = lane >> 3, scol = lane & 7;

    f4 acc[4][4] = {};

    for (int k0 = 0; k0 < Dv; k0 += 64) {
        #pragma unroll
        for (int c = 0; c < 4; c++) {
            int row = w * 32 + c * 8 + srow;
            int su = (scol ^ (row & 7)) << 3;
            gload16(&xb[(size_t)(m0 + row) * Dv + k0 + su], &As[(w * 32 + c * 8) * 64]);
            gload16(&Wb[(size_t)(n0 + row) * Dv + k0 + su], &Bs[(w * 32 + c * 8) * 64]);
        }
        __syncthreads();
        #pragma unroll
        for (int ks = 0; ks < 2; ks++) {
            sh8 fa[4], fb[4];
            #pragma unroll
            for (int mi = 0; mi < 4; mi++) {
                int r = wr * 64 + mi * 16 + tx;
                fa[mi] = *reinterpret_cast<const sh8*>(&As[(r * 64 + ks * 32 + g * 8) ^ ((r & 7) << 3)]);
            }
            #pragma unroll
            for (int ni = 0; ni < 4; ni++) {
                int r = wc * 64 + ni * 16 + tx;
                fb[ni] = *reinterpret_cast<const sh8*>(&Bs[(r * 64 + ks * 32 + g * 8) ^ ((r & 7) << 3)]);
            }
            if (z < 2) {
                #pragma unroll
                for (int mi = 0; mi < 4; mi++)
                    #pragma unroll
                    for (int ni = 0; ni < 4; ni++)
                        acc[mi][ni] = MFMA(fb[ni], fa[mi], acc[mi][ni]);   // C: row=n, col=m
            } else {
                #pragma unroll
                for (int mi = 0; mi < 4; mi++)
                    #pragma unroll
                    for (int ni = 0; ni < 4; ni++)
                        acc[mi][ni] = MFMA(fa[mi], fb[ni], acc[mi][ni]);   // C: row=m, col=n
            }
        }
        __syncthreads();
    }

    if (z < 2) {
        unsigned short* ob = (z == 0) ? qb : kb;
        const float sc = (z == 0) ? 0.1803368801f : 1.0f;   // 0.125*log2(e) into Q
        #pragma unroll
        for (int mi = 0; mi < 4; mi++)
            #pragma unroll
            for (int ni = 0; ni < 4; ni++) {
                int m = m0 + wr * 64 + mi * 16 + tx;          // col of C = x row
                int n = n0 + wc * 64 + ni * 16 + g * 4;       // row of C = W row (base)
                sh4 pkd;
                #pragma unroll
                for (int i = 0; i < 4; i++) pkd[i] = (short)bf16_rn(acc[mi][ni][i] * sc);
                *reinterpret_cast<sh4*>(&ob[(size_t)m * Dv + n]) = pkd;
            }
    } else {
        const int tb0 = ((m0 + wr * 64) & (Tv - 1));          // 64-aligned t-block
        const int b   = (m0 + wr * 64) >> 11;
        #pragma unroll
        for (int mi = 0; mi < 4; mi++)
            #pragma unroll
            for (int ni = 0; ni < 4; ni++) {
                // key = mi*16 + g*4 + i  ->  tau-slot = 32*(mi>>1) + 8g + 4*(mi&1) + i
                int t = tb0 + ((mi & 2) << 4) + (g << 3) + ((mi & 1) << 2);
                int n = n0 + wc * 64 + ni * 16 + tx;          // col of C = W row
                int h = n >> 6, dh = n & 63;
                sh4 pkd;
                #pragma unroll
                for (int i = 0; i < 4; i++) pkd[i] = (short)bf16_rn(acc[mi][ni][i]);
                *reinterpret_cast<sh4*>(&vtb[(((size_t)(b * Hv + h)) * DHv + dh) * Tv + t]) = pkd;
            }
    }
}

// ---------------------------------------------------------------------------
// Kernel 2: flash attention.  128-thread blocks: 2 waves x 4 q-groups x 16
// q-rows (QBLK=128, 512 blocks, 2 independent blocks/CU).  Per tile each wave
// loads kf/vf ONCE (16 ds_read_b128) and reuses them across 4 q-groups (64
// useful MFMA) -> DS:MFMA 1:4, per-CU LDS-port traffic halved vs round 8.
// Group chains QK->exp2->PV are independent across groups -> MFMA/VALU
// overlap within the wave.  Swapped QK^T, tau key-relabel keeps P entirely
// in registers; no-max softmax; l via ones-MFMA.  Dbuf K/V + XCD swizzle.
// ---------------------------------------------------------------------------
__global__ __launch_bounds__(128) void flash_mfma(
    const unsigned short* __restrict__ qbuf, const unsigned short* __restrict__ kb,
    const unsigned short* __restrict__ vtb,
    const unsigned short* __restrict__ pkb, const unsigned short* __restrict__ pvtb,
    unsigned short* __restrict__ yh, unsigned short* __restrict__ yl)
{
    __shared__ __align__(16) unsigned short Ks[2][64 * 64], Vs[2][64 * 64];
    const int tid = threadIdx.x;
    const int lane = tid & 63, w = tid >> 6;       // w in 0..1
    const int g = lane >> 4, tx = lane & 15;
    // XCD swizzle: 512 blocks, 8 XCDs, chunk=64 => 4 bh per XCD
    const int pblk = blockIdx.x;
    const int L = (pblk & 7) * 64 + (pblk >> 3);
    const int qt = L & 15;                 // 16 q-tiles of 128 rows
    const int bh = L >> 4;
    const int b = bh >> 4, h = bh & 15;
    const int srow = lane >> 3, scol = lane & 7;
    const int su = (scol ^ srow) << 3;     // row&7 == srow for all staged rows

    // Q frags: 4 groups x 2 ks (MFMA B-operand, pre-scaled by 0.125*log2e)
    sh8 qf[4][2];
    #pragma unroll
    for (int qg = 0; qg < 4; qg++) {
        size_t base = ((size_t)(b * Tv) + qt * 128 + w * 64 + qg * 16 + tx) * Dv + h * 64;
        qf[qg][0] = *reinterpret_cast<const sh8*>(&qbuf[base + g * 8]);
        qf[qg][1] = *reinterpret_cast<const sh8*>(&qbuf[base + 32 + g * 8]);
    }

    f4 o[4][4] = {};
    f4 ol[4] = {};                         // ones-colsum accumulators (l per group)
    sh8 onesf;
    #pragma unroll
    for (int j = 0; j < 8; j++) onesf[j] = (short)0x3F80;   // bf16 1.0

    // staging pointers: base covers row (w*32 + srow); call c adds 8 rows
    const unsigned short* kp = &pkb[((size_t)bh * Pv + w * 32 + srow) * DHv + su];
    const unsigned short* vp = &pvtb[((size_t)bh * DHv + w * 32 + srow) * Pv + su];
    int kcs = 8 * DHv;                     // per-call element steps (8 rows)
    int vcs = 8 * Pv;

    auto stage = [&](int buf) {
        unsigned short* kd = &Ks[buf][(w * 32) * 64];
        unsigned short* vd = &Vs[buf][(w * 32) * 64];
        #pragma unroll
        for (int c = 0; c < 4; c++) {
            gload16(kp + c * kcs, kd + c * 8 * 64);
            gload16(vp + c * vcs, vd + c * 8 * 64);
        }
    };
    auto advance = [&](int nt) {           // nt = tile just staged
        if (nt == 7) {                     // switch prefix -> computed arrays
            kp = &kb[((size_t)(b * Tv) + w * 32 + srow) * Dv + h * 64 + su];
            vp = &vtb[((size_t)bh * DHv + w * 32 + srow) * Tv + su];
            kcs = 8 * Dv; vcs = 8 * Tv;
        } else if (nt < 7) { kp += 64 * DHv; vp += 64; }
        else               { kp += 64 * Dv;  vp += 64; }
    };

    stage(0); advance(0);
    __syncthreads();          // vmcnt drain -> tile 0 resident
    int cur = 0;

    for (int t = 0; t < Lv / 64; t++) {
        if (t + 1 < Lv / 64) { stage(cur ^ 1); advance(t + 1); }

        // load K/V fragments once; reused by all 4 q-groups
        sh8 kf[8], vf[8];
        #pragma unroll
        for (int nf = 0; nf < 4; nf++) {
            int r = nf * 16 + tx;
            int x0 = (r * 64 + g * 8) ^ ((r & 7) << 3);
            int x1 = (r * 64 + 32 + g * 8) ^ ((r & 7) << 3);
            kf[nf]     = *reinterpret_cast<const sh8*>(&Ks[cur][x0]);
            kf[4 + nf] = *reinterpret_cast<const sh8*>(&Ks[cur][x1]);
            vf[nf]     = *reinterpret_cast<const sh8*>(&Vs[cur][x0]);
            vf[4 + nf] = *reinterpret_cast<const sh8*>(&Vs[cur][x1]);
        }

        #pragma unroll
        for (int qg = 0; qg < 4; qg++) {
            // S^T = K Q^T (keys nf*16+g*4+i, q=tx), halves to cap s/pf liveness
            f4 sa = {}, sb = {};
            sa = MFMA(kf[0], qf[qg][0], sa); sa = MFMA(kf[4], qf[qg][1], sa);
            sb = MFMA(kf[1], qf[qg][0], sb); sb = MFMA(kf[5], qf[qg][1], sb);
            sh8 pf0 = packP(sa, sb);                   // keys tau: ks=0 half
            f4 sc = {}, sd = {};
            sc = MFMA(kf[2], qf[qg][0], sc); sc = MFMA(kf[6], qf[qg][1], sc);
            sd = MFMA(kf[3], qf[qg][0], sd); sd = MFMA(kf[7], qf[qg][1], sd);
            sh8 pf1 = packP(sc, sd);                   // ks=1 half
            #pragma unroll
            for (int nf = 0; nf < 4; nf++) {
                o[qg][nf] = MFMA(vf[nf],     pf0, o[qg][nf]);
                o[qg][nf] = MFMA(vf[4 + nf], pf1, o[qg][nf]);
            }
            ol[qg] = MFMA(onesf, pf0, ol[qg]);
            ol[qg] = MFMA(onesf, pf1, ol[qg]);
        }
        __syncthreads();      // implicit vmcnt(0): next tile resident
        cur ^= 1;
    }

    // epilogue: y = O/l, split hi/lo, packed 8B stores
    #pragma unroll
    for (int qg = 0; qg < 4; qg++) {
        float inv = 1.0f / ol[qg][0];
        size_t ybase = ((size_t)(b * Tv) + qt * 128 + w * 64 + qg * 16 + tx) * Dv + h * 64;
        #pragma unroll
        for (int nf = 0; nf < 4; nf++) {
            sh4 ph, pl;
            #pragma unroll
            for (int i = 0; i < 4; i++) {
                float v = o[qg][nf][i] * inv;
                unsigned short hh = bf16_rn(v);
                ph[i] = (short)hh;
                pl[i] = (short)bf16_rn(v - bf16_f(hh));
            }
            *reinterpret_cast<sh4*>(&yh[ybase + nf * 16 + g * 4]) = ph;
            *reinterpret_cast<sh4*>(&yl[ybase + nf * 16 + g * 4]) = pl;
        }
    }
}

// ---------------------------------------------------------------------------
// Kernel 3: out = y @ Wo^T, fp32 out, 3-term split via K-extension:
// K' = 3072 over A={yh,yl,yh}, B={Woh,Woh,Wol}.  Single-buffered 24KB LDS.
// 2-D grid (reverted).
// ---------------------------------------------------------------------------
__global__ __launch_bounds__(256) void out_gemm(
    const unsigned short* __restrict__ yh, const unsigned short* __restrict__ yl,
    const unsigned short* __restrict__ woh, const unsigned short* __restrict__ wol,
    float* __restrict__ out)
{
    __shared__ __align__(16) unsigned short As[64 * 64], Bs[128 * 64];
    const int tid = threadIdx.x;
    const int lane = tid & 63, w = tid >> 6;
    const int g = lane >> 4, tx = lane & 15;
    const int wr = w >> 1, wc = w & 1;
    const int m0 = blockIdx.x * 64, n0 = blockIdx.y * 128;
    const int srow = lane >> 3, scol = lane & 7;

    f4 acc[2][4] = {};

    for (int k0 = 0; k0 < 3 * Dv; k0 += 64) {
        int seg = k0 >> 10, kk = k0 & (Dv - 1);
        const unsigned short* Asrc = (seg == 1) ? yl : yh;
        const unsigned short* Bsrc = (seg == 2) ? wol : woh;
        #pragma unroll
        for (int c = 0; c < 2; c++) {
            int row = w * 16 + c * 8 + srow;
            int su = (scol ^ (row & 7)) << 3;
            gload16(&Asrc[(size_t)(m0 + row) * Dv + kk + su], &As[(w * 16 + c * 8) * 64]);
        }
        #pragma unroll
        for (int c = 0; c < 4; c++) {
            int row = w * 32 + c * 8 + srow;
            int su = (scol ^ (row & 7)) << 3;
            gload16(&Bsrc[(size_t)(n0 + row) * Dv + kk + su], &Bs[(w * 32 + c * 8) * 64]);
        }
        __syncthreads();
        #pragma unroll
        for (int ks = 0; ks < 2; ks++) {
            sh8 fa[2], fb[4];
            #pragma unroll
            for (int mi = 0; mi < 2; mi++) {
                int r = wr * 32 + mi * 16 + tx;
                fa[mi] = *reinterpret_cast<const sh8*>(&As[(r * 64 + ks * 32 + g * 8) ^ ((r & 7) << 3)]);
            }
            #pragma unroll
            for (int ni = 0; ni < 4; ni++) {
                int r = wc * 64 + ni * 16 + tx;
                fb[ni] = *reinterpret_cast<const sh8*>(&Bs[(r * 64 + ks * 32 + g * 8) ^ ((r & 7) << 3)]);
            }
            #pragma unroll
            for (int mi = 0; mi < 2; mi++)
                #pragma unroll
                for (int ni = 0; ni < 4; ni++)
                    acc[mi][ni] = MFMA(fb[ni], fa[mi], acc[mi][ni]);   // C: row=n, col=m
        }
        __syncthreads();
    }

    #pragma unroll
    for (int mi = 0; mi < 2; mi++)
        #pragma unroll
        for (int ni = 0; ni < 4; ni++) {
            int m = m0 + wr * 32 + mi * 16 + tx;
            int n = n0 + wc * 64 + ni * 16 + g * 4;
            *reinterpret_cast<float4*>(&out[(size_t)m * Dv + n]) =
                make_float4(acc[mi][ni][0], acc[mi][ni][1], acc[mi][ni][2], acc[mi][ni][3]);
        }
}

// ---------------------------------------------------------------------------
extern "C" void kernel_launch(void* const* d_in, const int* in_sizes, int n_in,
                              void* d_out, int out_size, void* d_ws, size_t ws_size,
                              hipStream_t stream)
{
    const float* x  = (const float*)d_in[0];
    const float* pk = (const float*)d_in[1];
    const float* pv = (const float*)d_in[2];
    const float* Wq = (const float*)d_in[3];
    const float* Wk = (const float*)d_in[4];
    const float* Wv = (const float*)d_in[5];
    const float* Wo = (const float*)d_in[6];

    const size_t M1 = 1048576;
    unsigned short* ws  = (unsigned short*)d_ws;   // 31M ushorts = 62 MB
    unsigned short* xb   = ws;                     // 4M  [B*T, D]
    unsigned short* wqb  = ws + 4  * M1;           // 1M
    unsigned short* wkb  = ws + 5  * M1;
    unsigned short* wvb  = ws + 6  * M1;
    unsigned short* woh  = ws + 7  * M1;
    unsigned short* wol  = ws + 8  * M1;
    unsigned short* pkb  = ws + 9  * M1;           // [B,H,P,DH]
    unsigned short* pvtb = ws + 10 * M1;           // [B,H,DH,P] tau-permuted keys
    unsigned short* qb   = ws + 11 * M1;           // 4M [B,T,D] (pre-scaled by C)
    unsigned short* kb   = ws + 15 * M1;           // 4M [B,T,D]
    unsigned short* vtb  = ws + 19 * M1;           // 4M [B,H,DH,T] tau-permuted keys
    unsigned short* yh   = ws + 23 * M1;           // 4M [B,T,D]
    unsigned short* yl   = ws + 27 * M1;

    prep_convert<<<9216, 256, 0, stream>>>(x, Wq, Wk, Wv, pk, Wo,
                                           xb, wqb, wkb, wvb, pkb, woh, wol);
    prep_transpose<<<256, 256, 0, stream>>>(pv, pvtb);
    qkv_gemm<<<dim3(32, 8, 3), 256, 0, stream>>>(xb, wqb, wkb, wvb, qb, kb, vtb);
    flash_mfma<<<dim3(Bv * Hv * (Tv / 128)), 128, 0, stream>>>(qb, kb, vtb, pkb, pvtb, yh, yl);
    out_gemm<<<dim3(64, 8), 256, 0, stream>>>(yh, yl, woh, wol, (float*)d_out);
}

// Round 10
// 150.002 us; speedup vs baseline: 1.2082x; 1.2082x over previous
//
#include <hip/hip_runtime.h>
#include <cstdint>

#define Bv  2
#define Tv  2048
#define Dv  1024
#define Hv  16
#define DHv 64
#define Pv  512
#define Lv  2560   // P + T

typedef __attribute__((ext_vector_type(8))) short sh8;   // 8 bf16 MFMA frag
typedef __attribute__((ext_vector_type(4))) short sh4;
typedef __attribute__((ext_vector_type(4))) float f4;
typedef __attribute__((ext_vector_type(4))) unsigned int u4v;

#define MFMA(a,b,c) __builtin_amdgcn_mfma_f32_16x16x32_bf16(a,b,c,0,0,0)

__device__ __forceinline__ unsigned short bf16_rn(float f) {
    unsigned int u = __builtin_bit_cast(unsigned int, f);
    u += 0x7FFFu + ((u >> 16) & 1u);          // RTNE
    return (unsigned short)(u >> 16);
}
__device__ __forceinline__ float bf16_f(unsigned short h) {
    unsigned int u = ((unsigned int)h) << 16;
    return __builtin_bit_cast(float, u);
}
__device__ __forceinline__ unsigned int fbits(float f) {
    return __builtin_bit_cast(unsigned int, f);
}

// async global->LDS, 16B per lane; LDS dest = wave-uniform base + lane*16
__device__ __forceinline__ void gload16(const unsigned short* g, unsigned short* l) {
    __builtin_amdgcn_global_load_lds(
        (const __attribute__((address_space(1))) unsigned int*)(g),
        (__attribute__((address_space(3))) unsigned int*)(l),
        16, 0, 0);
}

// exp2 + truncate-pack two QK accumulators (8 P values) into one bf16 B-frag.
__device__ __forceinline__ sh8 packP(const f4 a, const f4 b) {
    float e0 = __builtin_amdgcn_exp2f(a[0]), e1 = __builtin_amdgcn_exp2f(a[1]);
    float e2 = __builtin_amdgcn_exp2f(a[2]), e3 = __builtin_amdgcn_exp2f(a[3]);
    float f0 = __builtin_amdgcn_exp2f(b[0]), f1 = __builtin_amdgcn_exp2f(b[1]);
    float f2 = __builtin_amdgcn_exp2f(b[2]), f3 = __builtin_amdgcn_exp2f(b[3]);
    u4v d;
    d[0] = __builtin_amdgcn_perm(fbits(e1), fbits(e0), 0x07060302u);
    d[1] = __builtin_amdgcn_perm(fbits(e3), fbits(e2), 0x07060302u);
    d[2] = __builtin_amdgcn_perm(fbits(f1), fbits(f0), 0x07060302u);
    d[3] = __builtin_amdgcn_perm(fbits(f3), fbits(f2), 0x07060302u);
    return __builtin_bit_cast(sh8, d);
}

// ---------------------------------------------------------------------------
// Prep 1: fp32 -> bf16 conversions (x, Wq, Wk, Wv, pk single; Wo -> hi/lo).
// ---------------------------------------------------------------------------
__global__ __launch_bounds__(256) void prep_convert(
    const float* __restrict__ x,  const float* __restrict__ Wq,
    const float* __restrict__ Wk, const float* __restrict__ Wv,
    const float* __restrict__ pk, const float* __restrict__ Wo,
    unsigned short* __restrict__ xb,  unsigned short* __restrict__ wqb,
    unsigned short* __restrict__ wkb, unsigned short* __restrict__ wvb,
    unsigned short* __restrict__ pkb, unsigned short* __restrict__ woh,
    unsigned short* __restrict__ wol)
{
    int i = blockIdx.x * 256 + threadIdx.x;   // float4 index, total 2359296
    const float* src; unsigned short* dst; int off; bool split = false;
    if      (i < 1048576) { src = x;  dst = xb;  off = i; }
    else if (i < 1310720) { src = Wq; dst = wqb; off = i - 1048576; }
    else if (i < 1572864) { src = Wk; dst = wkb; off = i - 1310720; }
    else if (i < 1835008) { src = Wv; dst = wvb; off = i - 1572864; }
    else if (i < 2097152) { src = pk; dst = pkb; off = i - 1835008; }
    else                  { src = Wo; dst = woh; off = i - 2097152; split = true; }
    float4 v = reinterpret_cast<const float4*>(src)[off];
    float vv[4] = {v.x, v.y, v.z, v.w};
    sh4 h, l;
    #pragma unroll
    for (int j = 0; j < 4; j++) {
        unsigned short hh = bf16_rn(vv[j]);
        h[j] = (short)hh;
        l[j] = (short)bf16_rn(vv[j] - bf16_f(hh));
    }
    reinterpret_cast<sh4*>(dst)[off] = h;
    if (split) reinterpret_cast<sh4*>(wol)[off] = l;
}

// ---------------------------------------------------------------------------
// Prep 2: pv [B,H,P,DH] fp32 -> pvtb [B,H,DH,P'] bf16, keys tau-permuted
// within each 64-tile.  For run u (keys 8u+j):
// slot(j<4) = 32*((u>>2)&1) + 16*(u&1) + 4*((u>>1)&1) + j, slot(j>=4) = +8.
// ---------------------------------------------------------------------------
__global__ __launch_bounds__(256) void prep_transpose(
    const float* __restrict__ pv, unsigned short* __restrict__ pvtb)
{
    __shared__ unsigned short Tls[64][66];
    const int tid = threadIdx.x;
    const int bh = blockIdx.x >> 3, pt = blockIdx.x & 7;
    #pragma unroll
    for (int i = 0; i < 4; i++) {
        int id = i * 256 + tid;
        int p = id >> 4, c4 = (id & 15) << 2;
        float4 v = *reinterpret_cast<const float4*>(
            &pv[((size_t)bh * Pv + pt * 64 + p) * DHv + c4]);
        Tls[c4+0][p] = bf16_rn(v.x);
        Tls[c4+1][p] = bf16_rn(v.y);
        Tls[c4+2][p] = bf16_rn(v.z);
        Tls[c4+3][p] = bf16_rn(v.w);
    }
    __syncthreads();
    #pragma unroll
    for (int i = 0; i < 2; i++) {
        int id = i * 256 + tid;
        int d = id >> 3, u = id & 7;             // dh row, 8-key run index
        sh4 lo, hi;
        #pragma unroll
        for (int j = 0; j < 4; j++) {
            lo[j] = (short)Tls[d][u * 8 + j];
            hi[j] = (short)Tls[d][u * 8 + 4 + j];
        }
        int p0 = ((u >> 2) & 1) * 32 + (u & 1) * 16 + ((u >> 1) & 1) * 4;
        size_t base = ((size_t)bh * DHv + d) * Pv + pt * 64;
        *reinterpret_cast<sh4*>(&pvtb[base + p0])     = lo;
        *reinterpret_cast<sh4*>(&pvtb[base + p0 + 8]) = hi;
    }
}

// ---------------------------------------------------------------------------
// Kernel 1: QKV projection, single-bf16 MFMA, m97 structure (single-buffered).
// Q pre-scaled by 0.125*log2(e); V^T stored tau-permuted per 64-tile.
// ---------------------------------------------------------------------------
__global__ __launch_bounds__(256) void qkv_gemm(
    const unsigned short* __restrict__ xb,
    const unsigned short* __restrict__ wqb, const unsigned short* __restrict__ wkb,
    const unsigned short* __restrict__ wvb,
    unsigned short* __restrict__ qb, unsigned short* __restrict__ kb,
    unsigned short* __restrict__ vtb)
{
    __shared__ __align__(16) unsigned short As[128 * 64], Bs[128 * 64];
    const int tid = threadIdx.x;
    const int lane = tid & 63, w = tid >> 6;
    const int g = lane >> 4, tx = lane & 15;
    const int wr = w >> 1, wc = w & 1;
    const int m0 = blockIdx.x * 128, n0 = blockIdx.y * 128;
    const int z = blockIdx.z;
    const unsigned short* Wb = (z == 0) ? wqb : (z == 1) ? wkb : wvb;
    const int srow = lane >> 3, scol = lane & 7;

    f4 acc[4][4] = {};

    for (int k0 = 0; k0 < Dv; k0 += 64) {
        #pragma unroll
        for (int c = 0; c < 4; c++) {
            int row = w * 32 + c * 8 + srow;
            int su = (scol ^ (row & 7)) << 3;
            gload16(&xb[(size_t)(m0 + row) * Dv + k0 + su], &As[(w * 32 + c * 8) * 64]);
            gload16(&Wb[(size_t)(n0 + row) * Dv + k0 + su], &Bs[(w * 32 + c * 8) * 64]);
        }
        __syncthreads();
        #pragma unroll
        for (int ks = 0; ks < 2; ks++) {
            sh8 fa[4], fb[4];
            #pragma unroll
            for (int mi = 0; mi < 4; mi++) {
                int r = wr * 64 + mi * 16 + tx;
                fa[mi] = *reinterpret_cast<const sh8*>(&As[(r * 64 + ks * 32 + g * 8) ^ ((r & 7) << 3)]);
            }
            #pragma unroll
            for (int ni = 0; ni < 4; ni++) {
                int r = wc * 64 + ni * 16 + tx;
                fb[ni] = *reinterpret_cast<const sh8*>(&Bs[(r * 64 + ks * 32 + g * 8) ^ ((r & 7) << 3)]);
            }
            if (z < 2) {
                #pragma unroll
                for (int mi = 0; mi < 4; mi++)
                    #pragma unroll
                    for (int ni = 0; ni < 4; ni++)
                        acc[mi][ni] = MFMA(fb[ni], fa[mi], acc[mi][ni]);   // C: row=n, col=m
            } else {
                #pragma unroll
                for (int mi = 0; mi < 4; mi++)
                    #pragma unroll
                    for (int ni = 0; ni < 4; ni++)
                        acc[mi][ni] = MFMA(fa[mi], fb[ni], acc[mi][ni]);   // C: row=m, col=n
            }
        }
        __syncthreads();
    }

    if (z < 2) {
        unsigned short* ob = (z == 0) ? qb : kb;
        const float sc = (z == 0) ? 0.1803368801f : 1.0f;   // 0.125*log2(e) into Q
        #pragma unroll
        for (int mi = 0; mi < 4; mi++)
            #pragma unroll
            for (int ni = 0; ni < 4; ni++) {
                int m = m0 + wr * 64 + mi * 16 + tx;          // col of C = x row
                int n = n0 + wc * 64 + ni * 16 + g * 4;       // row of C = W row (base)
                sh4 pkd;
                #pragma unroll
                for (int i = 0; i < 4; i++) pkd[i] = (short)bf16_rn(acc[mi][ni][i] * sc);
                *reinterpret_cast<sh4*>(&ob[(size_t)m * Dv + n]) = pkd;
            }
    } else {
        const int tb0 = ((m0 + wr * 64) & (Tv - 1));          // 64-aligned t-block
        const int b   = (m0 + wr * 64) >> 11;
        #pragma unroll
        for (int mi = 0; mi < 4; mi++)
            #pragma unroll
            for (int ni = 0; ni < 4; ni++) {
                // key = mi*16 + g*4 + i  ->  tau-slot = 32*(mi>>1) + 8g + 4*(mi&1) + i
                int t = tb0 + ((mi & 2) << 4) + (g << 3) + ((mi & 1) << 2);
                int n = n0 + wc * 64 + ni * 16 + tx;          // col of C = W row
                int h = n >> 6, dh = n & 63;
                sh4 pkd;
                #pragma unroll
                for (int i = 0; i < 4; i++) pkd[i] = (short)bf16_rn(acc[mi][ni][i]);
                *reinterpret_cast<sh4*>(&vtb[(((size_t)(b * Hv + h)) * DHv + dh) * Tv + t]) = pkd;
            }
    }
}

// ---------------------------------------------------------------------------
// Kernel 2: flash attention.  KEY-SPLIT: 256-thread blocks, 4 waves (kw,qw):
// wave handles keys 32*kw..+31 (half the K/V tile -> 8 ds_read_b128/tile,
// half of round 8) x q-rows qw*64..+63 (4 groups of 16).  TLP unchanged vs
// round 8 (512 blocks, 2 blocks/CU, 8 waves/CU) -- round 9's occupancy
// collapse avoided.  tau key-relabel keeps P in registers (wave kw's keys
// occupy exactly V-columns 32kw..+31).  O/l partial over keys -> one
// cross-wave LDS reduction at the end (Ks/Vs reused as scratch).
// No-max softmax; l via ones-MFMA.  Dbuf K/V + XCD swizzle.  LDS 34KB.
// ---------------------------------------------------------------------------
__global__ __launch_bounds__(256) void flash_mfma(
    const unsigned short* __restrict__ qbuf, const unsigned short* __restrict__ kb,
    const unsigned short* __restrict__ vtb,
    const unsigned short* __restrict__ pkb, const unsigned short* __restrict__ pvtb,
    unsigned short* __restrict__ yh, unsigned short* __restrict__ yl)
{
    __shared__ __align__(16) unsigned short Ks[2][64 * 64], Vs[2][64 * 64];
    __shared__ float olex[2][4][64];
    const int tid = threadIdx.x;
    const int lane = tid & 63, w = tid >> 6;       // 4 waves
    const int kw = w & 1, qw = w >> 1;             // key-half, q-half
    const int g = lane >> 4, tx = lane & 15;
    // XCD swizzle: 512 blocks, 8 XCDs, chunk=64 => 4 bh per XCD
    const int pblk = blockIdx.x;
    const int L = (pblk & 7) * 64 + (pblk >> 3);
    const int qt = L & 15;                 // 16 q-tiles of 128 rows
    const int bh = L >> 4;
    const int b = bh >> 4, h = bh & 15;
    const int srow = lane >> 3, scol = lane & 7;

    // Q frags: 4 groups x 2 dh-halves (MFMA B-operand, pre-scaled)
    sh8 qf[4][2];
    #pragma unroll
    for (int qg = 0; qg < 4; qg++) {
        size_t base = ((size_t)(b * Tv) + qt * 128 + qw * 64 + qg * 16 + tx) * Dv + h * 64;
        qf[qg][0] = *reinterpret_cast<const sh8*>(&qbuf[base + g * 8]);
        qf[qg][1] = *reinterpret_cast<const sh8*>(&qbuf[base + 32 + g * 8]);
    }

    f4 o[4][4] = {};          // [q-group][dh-frag], partial over this wave's keys
    f4 ol[4] = {};            // ones-colsum accumulators (partial l per group)
    sh8 onesf;
    #pragma unroll
    for (int j = 0; j < 8; j++) onesf[j] = (short)0x3F80;   // bf16 1.0

    // staging pointers (wave stages rows w*16..+15 of both K and V tiles)
    const int r0 = w * 16 + srow, r1 = r0 + 8;
    const int su0 = (scol ^ (r0 & 7)) << 3;
    const int su1 = (scol ^ (r1 & 7)) << 3;
    const unsigned short* ka0 = &pkb[((size_t)bh * Pv + r0) * DHv + su0];
    const unsigned short* ka1 = &pkb[((size_t)bh * Pv + r1) * DHv + su1];
    const unsigned short* va0 = &pvtb[((size_t)bh * DHv + r0) * Pv + su0];
    const unsigned short* va1 = &pvtb[((size_t)bh * DHv + r1) * Pv + su1];

    auto stage = [&](int buf) {
        gload16(ka0, &Ks[buf][(w * 16    ) * 64]);
        gload16(ka1, &Ks[buf][(w * 16 + 8) * 64]);
        gload16(va0, &Vs[buf][(w * 16    ) * 64]);
        gload16(va1, &Vs[buf][(w * 16 + 8) * 64]);
    };
    auto advance = [&](int nt) {           // nt = tile just staged
        if (nt == 7) {                     // switch prefix -> computed arrays
            ka0 = &kb[((size_t)(b * Tv) + r0) * Dv + h * 64 + su0];
            ka1 = &kb[((size_t)(b * Tv) + r1) * Dv + h * 64 + su1];
            va0 = &vtb[((size_t)bh * DHv + r0) * Tv + su0];
            va1 = &vtb[((size_t)bh * DHv + r1) * Tv + su1];
        } else if (nt < 7) { ka0 += 64 * DHv; ka1 += 64 * DHv; va0 += 64; va1 += 64; }
        else               { ka0 += 64 * Dv;  ka1 += 64 * Dv;  va0 += 64; va1 += 64; }
    };

    stage(0); advance(0);
    __syncthreads();          // vmcnt drain -> tile 0 resident
    int cur = 0;

    for (int t = 0; t < Lv / 64; t++) {
        if (t + 1 < Lv / 64) { stage(cur ^ 1); advance(t + 1); }

        // this wave's half of K (2 nf x 2 dh-halves) and V (4 nf x 32-key cols)
        sh8 kf[2][2], vf[4];
        #pragma unroll
        for (int nf = 0; nf < 2; nf++) {
            int rk = 32 * kw + nf * 16 + tx;
            kf[nf][0] = *reinterpret_cast<const sh8*>(
                &Ks[cur][(rk * 64 + g * 8) ^ ((rk & 7) << 3)]);
            kf[nf][1] = *reinterpret_cast<const sh8*>(
                &Ks[cur][(rk * 64 + 32 + g * 8) ^ ((rk & 7) << 3)]);
        }
        #pragma unroll
        for (int nf = 0; nf < 4; nf++) {
            int rv = nf * 16 + tx;
            vf[nf] = *reinterpret_cast<const sh8*>(
                &Vs[cur][(rv * 64 + 32 * kw + g * 8) ^ ((rv & 7) << 3)]);
        }

        #pragma unroll
        for (int qg = 0; qg < 4; qg++) {
            // S^T for this wave's 32 keys (a = 2kw+nf'), q = tx
            f4 sa = {}, sb = {};
            sa = MFMA(kf[0][0], qf[qg][0], sa); sa = MFMA(kf[0][1], qf[qg][1], sa);
            sb = MFMA(kf[1][0], qf[qg][0], sb); sb = MFMA(kf[1][1], qf[qg][1], sb);
            sh8 pf = packP(sa, sb);            // tau-slots 32kw + 8g + 4nf' + i
            #pragma unroll
            for (int nf = 0; nf < 4; nf++)
                o[qg][nf] = MFMA(vf[nf], pf, o[qg][nf]);
            ol[qg] = MFMA(onesf, pf, ol[qg]);
        }
        __syncthreads();      // implicit vmcnt(0): next tile resident
        cur ^= 1;
    }

    // cross-wave (kw) reduction: kw=1 writes partials to dead Ks/Vs, kw=0 adds
    float* ex = qw ? reinterpret_cast<float*>(Vs) : reinterpret_cast<float*>(Ks);
    if (kw) {
        #pragma unroll
        for (int qg = 0; qg < 4; qg++) {
            #pragma unroll
            for (int nf = 0; nf < 4; nf++)
                *reinterpret_cast<f4*>(&ex[((qg * 4 + nf) * 64 + lane) * 4]) = o[qg][nf];
            olex[qw][qg][lane] = ol[qg][0];
        }
    }
    __syncthreads();
    if (!kw) {
        #pragma unroll
        for (int qg = 0; qg < 4; qg++) {
            float l = ol[qg][0] + olex[qw][qg][lane];
            float inv = 1.0f / l;
            size_t ybase = ((size_t)(b * Tv) + qt * 128 + qw * 64 + qg * 16 + tx) * Dv + h * 64;
            #pragma unroll
            for (int nf = 0; nf < 4; nf++) {
                f4 op = o[qg][nf] +
                    *reinterpret_cast<const f4*>(&ex[((qg * 4 + nf) * 64 + lane) * 4]);
                sh4 ph, pl;
                #pragma unroll
                for (int i = 0; i < 4; i++) {
                    float v = op[i] * inv;
                    unsigned short hh = bf16_rn(v);
                    ph[i] = (short)hh;
                    pl[i] = (short)bf16_rn(v - bf16_f(hh));
                }
                *reinterpret_cast<sh4*>(&yh[ybase + nf * 16 + g * 4]) = ph;
                *reinterpret_cast<sh4*>(&yl[ybase + nf * 16 + g * 4]) = pl;
            }
        }
    }
}

// ---------------------------------------------------------------------------
// Kernel 3: out = y @ Wo^T, fp32 out, 3-term split via K-extension:
// K' = 3072 over A={yh,yl,yh}, B={Woh,Woh,Wol}.  Single-buffered 24KB LDS.
// ---------------------------------------------------------------------------
__global__ __launch_bounds__(256) void out_gemm(
    const unsigned short* __restrict__ yh, const unsigned short* __restrict__ yl,
    const unsigned short* __restrict__ woh, const unsigned short* __restrict__ wol,
    float* __restrict__ out)
{
    __shared__ __align__(16) unsigned short As[64 * 64], Bs[128 * 64];
    const int tid = threadIdx.x;
    const int lane = tid & 63, w = tid >> 6;
    const int g = lane >> 4, tx = lane & 15;
    const int wr = w >> 1, wc = w & 1;
    const int m0 = blockIdx.x * 64, n0 = blockIdx.y * 128;
    const int srow = lane >> 3, scol = lane & 7;

    f4 acc[2][4] = {};

    for (int k0 = 0; k0 < 3 * Dv; k0 += 64) {
        int seg = k0 >> 10, kk = k0 & (Dv - 1);
        const unsigned short* Asrc = (seg == 1) ? yl : yh;
        const unsigned short* Bsrc = (seg == 2) ? wol : woh;
        #pragma unroll
        for (int c = 0; c < 2; c++) {
            int row = w * 16 + c * 8 + srow;
            int su = (scol ^ (row & 7)) << 3;
            gload16(&Asrc[(size_t)(m0 + row) * Dv + kk + su], &As[(w * 16 + c * 8) * 64]);
        }
        #pragma unroll
        for (int c = 0; c < 4; c++) {
            int row = w * 32 + c * 8 + srow;
            int su = (scol ^ (row & 7)) << 3;
            gload16(&Bsrc[(size_t)(n0 + row) * Dv + kk + su], &Bs[(w * 32 + c * 8) * 64]);
        }
        __syncthreads();
        #pragma unroll
        for (int ks = 0; ks < 2; ks++) {
            sh8 fa[2], fb[4];
            #pragma unroll
            for (int mi = 0; mi < 2; mi++) {
                int r = wr * 32 + mi * 16 + tx;
                fa[mi] = *reinterpret_cast<const sh8*>(&As[(r * 64 + ks * 32 + g * 8) ^ ((r & 7) << 3)]);
            }
            #pragma unroll
            for (int ni = 0; ni < 4; ni++) {
                int r = wc * 64 + ni * 16 + tx;
                fb[ni] = *reinterpret_cast<const sh8*>(&Bs[(r * 64 + ks * 32 + g * 8) ^ ((r & 7) << 3)]);
            }
            #pragma unroll
            for (int mi = 0; mi < 2; mi++)
                #pragma unroll
                for (int ni = 0; ni < 4; ni++)
                    acc[mi][ni] = MFMA(fb[ni], fa[mi], acc[mi][ni]);   // C: row=n, col=m
        }
        __syncthreads();
    }

    #pragma unroll
    for (int mi = 0; mi < 2; mi++)
        #pragma unroll
        for (int ni = 0; ni < 4; ni++) {
            int m = m0 + wr * 32 + mi * 16 + tx;
            int n = n0 + wc * 64 + ni * 16 + g * 4;
            *reinterpret_cast<float4*>(&out[(size_t)m * Dv + n]) =
                make_float4(acc[mi][ni][0], acc[mi][ni][1], acc[mi][ni][2], acc[mi][ni][3]);
        }
}

// ---------------------------------------------------------------------------
extern "C" void kernel_launch(void* const* d_in, const int* in_sizes, int n_in,
                              void* d_out, int out_size, void* d_ws, size_t ws_size,
                              hipStream_t stream)
{
    const float* x  = (const float*)d_in[0];
    const float* pk = (const float*)d_in[1];
    const float* pv = (const float*)d_in[2];
    const float* Wq = (const float*)d_in[3];
    const float* Wk = (const float*)d_in[4];
    const float* Wv = (const float*)d_in[5];
    const float* Wo = (const float*)d_in[6];

    const size_t M1 = 1048576;
    unsigned short* ws  = (unsigned short*)d_ws;   // 31M ushorts = 62 MB
    unsigned short* xb   = ws;                     // 4M  [B*T, D]
    unsigned short* wqb  = ws + 4  * M1;           // 1M
    unsigned short* wkb  = ws + 5  * M1;
    unsigned short* wvb  = ws + 6  * M1;
    unsigned short* woh  = ws + 7  * M1;
    unsigned short* wol  = ws + 8  * M1;
    unsigned short* pkb  = ws + 9  * M1;           // [B,H,P,DH]
    unsigned short* pvtb = ws + 10 * M1;           // [B,H,DH,P] tau-permuted keys
    unsigned short* qb   = ws + 11 * M1;           // 4M [B,T,D] (pre-scaled by C)
    unsigned short* kb   = ws + 15 * M1;           // 4M [B,T,D]
    unsigned short* vtb  = ws + 19 * M1;           // 4M [B,H,DH,T] tau-permuted keys
    unsigned short* yh   = ws + 23 * M1;           // 4M [B,T,D]
    unsigned short* yl   = ws + 27 * M1;

    prep_convert<<<9216, 256, 0, stream>>>(x, Wq, Wk, Wv, pk, Wo,
                                           xb, wqb, wkb, wvb, pkb, woh, wol);
    prep_transpose<<<256, 256, 0, stream>>>(pv, pvtb);
    qkv_gemm<<<dim3(32, 8, 3), 256, 0, stream>>>(xb, wqb, wkb, wvb, qb, kb, vtb);
    flash_mfma<<<dim3(Bv * Hv * (Tv / 128)), 256, 0, stream>>>(qb, kb, vtb, pkb, pvtb, yh, yl);
    out_gemm<<<dim3(64, 8), 256, 0, stream>>>(yh, yl, woh, wol, (float*)d_out);
}

// Round 11
// 121.000 us; speedup vs baseline: 1.4978x; 1.2397x over previous
//
#include <hip/hip_runtime.h>
#include <cstdint>

#define Bv  2
#define Tv  2048
#define Dv  1024
#define Hv  16
#define DHv 64
#define Pv  512
#define Lv  2560   // P + T

typedef __attribute__((ext_vector_type(8))) short sh8;   // 8 bf16 MFMA frag
typedef __attribute__((ext_vector_type(4))) short sh4;
typedef __attribute__((ext_vector_type(4))) float f4;
typedef __attribute__((ext_vector_type(4))) unsigned int u4v;

#define MFMA(a,b,c) __builtin_amdgcn_mfma_f32_16x16x32_bf16(a,b,c,0,0,0)

__device__ __forceinline__ unsigned short bf16_rn(float f) {
    unsigned int u = __builtin_bit_cast(unsigned int, f);
    u += 0x7FFFu + ((u >> 16) & 1u);          // RTNE
    return (unsigned short)(u >> 16);
}
__device__ __forceinline__ float bf16_f(unsigned short h) {
    unsigned int u = ((unsigned int)h) << 16;
    return __builtin_bit_cast(float, u);
}
__device__ __forceinline__ unsigned int fbits(float f) {
    return __builtin_bit_cast(unsigned int, f);
}

// async global->LDS, 16B per lane; LDS dest = wave-uniform base + lane*16
__device__ __forceinline__ void gload16(const unsigned short* g, unsigned short* l) {
    __builtin_amdgcn_global_load_lds(
        (const __attribute__((address_space(1))) unsigned int*)(g),
        (__attribute__((address_space(3))) unsigned int*)(l),
        16, 0, 0);
}

// exp2 + truncate-pack two QK accumulators (8 P values) into one bf16 B-frag.
__device__ __forceinline__ sh8 packP(const f4 a, const f4 b) {
    float e0 = __builtin_amdgcn_exp2f(a[0]), e1 = __builtin_amdgcn_exp2f(a[1]);
    float e2 = __builtin_amdgcn_exp2f(a[2]), e3 = __builtin_amdgcn_exp2f(a[3]);
    float f0 = __builtin_amdgcn_exp2f(b[0]), f1 = __builtin_amdgcn_exp2f(b[1]);
    float f2 = __builtin_amdgcn_exp2f(b[2]), f3 = __builtin_amdgcn_exp2f(b[3]);
    u4v d;
    d[0] = __builtin_amdgcn_perm(fbits(e1), fbits(e0), 0x07060302u);
    d[1] = __builtin_amdgcn_perm(fbits(e3), fbits(e2), 0x07060302u);
    d[2] = __builtin_amdgcn_perm(fbits(f1), fbits(f0), 0x07060302u);
    d[3] = __builtin_amdgcn_perm(fbits(f3), fbits(f2), 0x07060302u);
    return __builtin_bit_cast(sh8, d);
}

// ---------------------------------------------------------------------------
// Prep 1: fp32 -> bf16 conversions (x, Wq, Wk, Wv, pk, Wo -- all single bf16).
// ---------------------------------------------------------------------------
__global__ __launch_bounds__(256) void prep_convert(
    const float* __restrict__ x,  const float* __restrict__ Wq,
    const float* __restrict__ Wk, const float* __restrict__ Wv,
    const float* __restrict__ pk, const float* __restrict__ Wo,
    unsigned short* __restrict__ xb,  unsigned short* __restrict__ wqb,
    unsigned short* __restrict__ wkb, unsigned short* __restrict__ wvb,
    unsigned short* __restrict__ pkb, unsigned short* __restrict__ woh)
{
    int i = blockIdx.x * 256 + threadIdx.x;   // float4 index, total 2359296
    const float* src; unsigned short* dst; int off;
    if      (i < 1048576) { src = x;  dst = xb;  off = i; }
    else if (i < 1310720) { src = Wq; dst = wqb; off = i - 1048576; }
    else if (i < 1572864) { src = Wk; dst = wkb; off = i - 1310720; }
    else if (i < 1835008) { src = Wv; dst = wvb; off = i - 1572864; }
    else if (i < 2097152) { src = pk; dst = pkb; off = i - 1835008; }
    else                  { src = Wo; dst = woh; off = i - 2097152; }
    float4 v = reinterpret_cast<const float4*>(src)[off];
    sh4 h;
    h[0] = (short)bf16_rn(v.x); h[1] = (short)bf16_rn(v.y);
    h[2] = (short)bf16_rn(v.z); h[3] = (short)bf16_rn(v.w);
    reinterpret_cast<sh4*>(dst)[off] = h;
}

// ---------------------------------------------------------------------------
// Prep 2: pv [B,H,P,DH] fp32 -> pvtb [B,H,DH,P'] bf16, keys tau-permuted
// within each 64-tile.  For run u (keys 8u+j):
// slot(j<4) = 32*((u>>2)&1) + 16*(u&1) + 4*((u>>1)&1) + j, slot(j>=4) = +8.
// ---------------------------------------------------------------------------
__global__ __launch_bounds__(256) void prep_transpose(
    const float* __restrict__ pv, unsigned short* __restrict__ pvtb)
{
    __shared__ unsigned short Tls[64][66];
    const int tid = threadIdx.x;
    const int bh = blockIdx.x >> 3, pt = blockIdx.x & 7;
    #pragma unroll
    for (int i = 0; i < 4; i++) {
        int id = i * 256 + tid;
        int p = id >> 4, c4 = (id & 15) << 2;
        float4 v = *reinterpret_cast<const float4*>(
            &pv[((size_t)bh * Pv + pt * 64 + p) * DHv + c4]);
        Tls[c4+0][p] = bf16_rn(v.x);
        Tls[c4+1][p] = bf16_rn(v.y);
        Tls[c4+2][p] = bf16_rn(v.z);
        Tls[c4+3][p] = bf16_rn(v.w);
    }
    __syncthreads();
    #pragma unroll
    for (int i = 0; i < 2; i++) {
        int id = i * 256 + tid;
        int d = id >> 3, u = id & 7;             // dh row, 8-key run index
        sh4 lo, hi;
        #pragma unroll
        for (int j = 0; j < 4; j++) {
            lo[j] = (short)Tls[d][u * 8 + j];
            hi[j] = (short)Tls[d][u * 8 + 4 + j];
        }
        int p0 = ((u >> 2) & 1) * 32 + (u & 1) * 16 + ((u >> 1) & 1) * 4;
        size_t base = ((size_t)bh * DHv + d) * Pv + pt * 64;
        *reinterpret_cast<sh4*>(&pvtb[base + p0])     = lo;
        *reinterpret_cast<sh4*>(&pvtb[base + p0 + 8]) = hi;
    }
}

// ---------------------------------------------------------------------------
// Kernel 1: QKV projection, single-bf16 MFMA, m97 structure (single-buffered).
// Q pre-scaled by 0.125*log2(e); V^T stored tau-permuted per 64-tile.
// ---------------------------------------------------------------------------
__global__ __launch_bounds__(256) void qkv_gemm(
    const unsigned short* __restrict__ xb,
    const unsigned short* __restrict__ wqb, const unsigned short* __restrict__ wkb,
    const unsigned short* __restrict__ wvb,
    unsigned short* __restrict__ qb, unsigned short* __restrict__ kb,
    unsigned short* __restrict__ vtb)
{
    __shared__ __align__(16) unsigned short As[128 * 64], Bs[128 * 64];
    const int tid = threadIdx.x;
    const int lane = tid & 63, w = tid >> 6;
    const int g = lane >> 4, tx = lane & 15;
    const int wr = w >> 1, wc = w & 1;
    const int m0 = blockIdx.x * 128, n0 = blockIdx.y * 128;
    const int z = blockIdx.z;
    const unsigned short* Wb = (z == 0) ? wqb : (z == 1) ? wkb : wvb;
    const int srow = lane >> 3, scol = lane & 7;

    f4 acc[4][4] = {};

    for (int k0 = 0; k0 < Dv; k0 += 64) {
        #pragma unroll
        for (int c = 0; c < 4; c++) {
            int row = w * 32 + c * 8 + srow;
            int su = (scol ^ (row & 7)) << 3;
            gload16(&xb[(size_t)(m0 + row) * Dv + k0 + su], &As[(w * 32 + c * 8) * 64]);
            gload16(&Wb[(size_t)(n0 + row) * Dv + k0 + su], &Bs[(w * 32 + c * 8) * 64]);
        }
        __syncthreads();
        #pragma unroll
        for (int ks = 0; ks < 2; ks++) {
            sh8 fa[4], fb[4];
            #pragma unroll
            for (int mi = 0; mi < 4; mi++) {
                int r = wr * 64 + mi * 16 + tx;
                fa[mi] = *reinterpret_cast<const sh8*>(&As[(r * 64 + ks * 32 + g * 8) ^ ((r & 7) << 3)]);
            }
            #pragma unroll
            for (int ni = 0; ni < 4; ni++) {
                int r = wc * 64 + ni * 16 + tx;
                fb[ni] = *reinterpret_cast<const sh8*>(&Bs[(r * 64 + ks * 32 + g * 8) ^ ((r & 7) << 3)]);
            }
            if (z < 2) {
                #pragma unroll
                for (int mi = 0; mi < 4; mi++)
                    #pragma unroll
                    for (int ni = 0; ni < 4; ni++)
                        acc[mi][ni] = MFMA(fb[ni], fa[mi], acc[mi][ni]);   // C: row=n, col=m
            } else {
                #pragma unroll
                for (int mi = 0; mi < 4; mi++)
                    #pragma unroll
                    for (int ni = 0; ni < 4; ni++)
                        acc[mi][ni] = MFMA(fa[mi], fb[ni], acc[mi][ni]);   // C: row=m, col=n
            }
        }
        __syncthreads();
    }

    if (z < 2) {
        unsigned short* ob = (z == 0) ? qb : kb;
        const float sc = (z == 0) ? 0.1803368801f : 1.0f;   // 0.125*log2(e) into Q
        #pragma unroll
        for (int mi = 0; mi < 4; mi++)
            #pragma unroll
            for (int ni = 0; ni < 4; ni++) {
                int m = m0 + wr * 64 + mi * 16 + tx;          // col of C = x row
                int n = n0 + wc * 64 + ni * 16 + g * 4;       // row of C = W row (base)
                sh4 pkd;
                #pragma unroll
                for (int i = 0; i < 4; i++) pkd[i] = (short)bf16_rn(acc[mi][ni][i] * sc);
                *reinterpret_cast<sh4*>(&ob[(size_t)m * Dv + n]) = pkd;
            }
    } else {
        const int tb0 = ((m0 + wr * 64) & (Tv - 1));          // 64-aligned t-block
        const int b   = (m0 + wr * 64) >> 11;
        #pragma unroll
        for (int mi = 0; mi < 4; mi++)
            #pragma unroll
            for (int ni = 0; ni < 4; ni++) {
                // key = mi*16 + g*4 + i  ->  tau-slot = 32*(mi>>1) + 8g + 4*(mi&1) + i
                int t = tb0 + ((mi & 2) << 4) + (g << 3) + ((mi & 1) << 2);
                int n = n0 + wc * 64 + ni * 16 + tx;          // col of C = W row
                int h = n >> 6, dh = n & 63;
                sh4 pkd;
                #pragma unroll
                for (int i = 0; i < 4; i++) pkd[i] = (short)bf16_rn(acc[mi][ni][i]);
                *reinterpret_cast<sh4*>(&vtb[(((size_t)(b * Hv + h)) * DHv + dh) * Tv + t]) = pkd;
            }
    }
}

// ---------------------------------------------------------------------------
// Kernel 2: flash attention.  KEY-SPLIT (round 10) + COUNTED-VMCNT BARRIERS:
// raw s_barrier with s_waitcnt vmcnt(4) (previous tile's 4 gload16 landed)
// instead of __syncthreads' full vmcnt(0) drain -- the just-issued next-tile
// loads stay in flight across the barrier (T4 pattern).  Last tile peeled
// with vmcnt(0).  Same two barriers/tile as before; sched_barrier(0) fences
// keep compiler ds_reads inside their phase.  tau key-relabel keeps P in
// registers; no-max softmax; l via ones-MFMA; epilogue writes SINGLE bf16 y
// (hi/lo dropped -- error analysis: sigma(y)~0.014, bf16 suffices).
// ---------------------------------------------------------------------------
__global__ __launch_bounds__(256) void flash_mfma(
    const unsigned short* __restrict__ qbuf, const unsigned short* __restrict__ kb,
    const unsigned short* __restrict__ vtb,
    const unsigned short* __restrict__ pkb, const unsigned short* __restrict__ pvtb,
    unsigned short* __restrict__ yh)
{
    __shared__ __align__(16) unsigned short Ks[2][64 * 64], Vs[2][64 * 64];
    __shared__ float olex[2][4][64];
    const int tid = threadIdx.x;
    const int lane = tid & 63, w = tid >> 6;       // 4 waves
    const int kw = w & 1, qw = w >> 1;             // key-half, q-half
    const int g = lane >> 4, tx = lane & 15;
    // XCD swizzle: 512 blocks, 8 XCDs, chunk=64 => 4 bh per XCD
    const int pblk = blockIdx.x;
    const int L = (pblk & 7) * 64 + (pblk >> 3);
    const int qt = L & 15;                 // 16 q-tiles of 128 rows
    const int bh = L >> 4;
    const int b = bh >> 4, h = bh & 15;
    const int srow = lane >> 3, scol = lane & 7;

    // Q frags: 4 groups x 2 dh-halves (MFMA B-operand, pre-scaled)
    sh8 qf[4][2];
    #pragma unroll
    for (int qg = 0; qg < 4; qg++) {
        size_t base = ((size_t)(b * Tv) + qt * 128 + qw * 64 + qg * 16 + tx) * Dv + h * 64;
        qf[qg][0] = *reinterpret_cast<const sh8*>(&qbuf[base + g * 8]);
        qf[qg][1] = *reinterpret_cast<const sh8*>(&qbuf[base + 32 + g * 8]);
    }

    f4 o[4][4] = {};          // [q-group][dh-frag], partial over this wave's keys
    f4 ol[4] = {};            // ones-colsum accumulators (partial l per group)
    sh8 onesf;
    #pragma unroll
    for (int j = 0; j < 8; j++) onesf[j] = (short)0x3F80;   // bf16 1.0

    // staging pointers (wave stages rows w*16..+15 of both K and V tiles)
    const int r0 = w * 16 + srow, r1 = r0 + 8;
    const int su0 = (scol ^ (r0 & 7)) << 3;
    const int su1 = (scol ^ (r1 & 7)) << 3;
    const unsigned short* ka0 = &pkb[((size_t)bh * Pv + r0) * DHv + su0];
    const unsigned short* ka1 = &pkb[((size_t)bh * Pv + r1) * DHv + su1];
    const unsigned short* va0 = &pvtb[((size_t)bh * DHv + r0) * Pv + su0];
    const unsigned short* va1 = &pvtb[((size_t)bh * DHv + r1) * Pv + su1];

    auto stage = [&](int buf) {            // 4 gload16 per wave per tile
        gload16(ka0, &Ks[buf][(w * 16    ) * 64]);
        gload16(ka1, &Ks[buf][(w * 16 + 8) * 64]);
        gload16(va0, &Vs[buf][(w * 16    ) * 64]);
        gload16(va1, &Vs[buf][(w * 16 + 8) * 64]);
    };
    auto advance = [&](int nt) {           // nt = tile just staged
        if (nt == 7) {                     // switch prefix -> computed arrays
            ka0 = &kb[((size_t)(b * Tv) + r0) * Dv + h * 64 + su0];
            ka1 = &kb[((size_t)(b * Tv) + r1) * Dv + h * 64 + su1];
            va0 = &vtb[((size_t)bh * DHv + r0) * Tv + su0];
            va1 = &vtb[((size_t)bh * DHv + r1) * Tv + su1];
        } else if (nt < 7) { ka0 += 64 * DHv; ka1 += 64 * DHv; va0 += 64; va1 += 64; }
        else               { ka0 += 64 * Dv;  ka1 += 64 * Dv;  va0 += 64; va1 += 64; }
    };

    auto compute = [&](int cur) {
        // this wave's half of K (2 nf x 2 dh-halves) and V (4 nf x 32-key cols)
        sh8 kf[2][2], vf[4];
        #pragma unroll
        for (int nf = 0; nf < 2; nf++) {
            int rk = 32 * kw + nf * 16 + tx;
            kf[nf][0] = *reinterpret_cast<const sh8*>(
                &Ks[cur][(rk * 64 + g * 8) ^ ((rk & 7) << 3)]);
            kf[nf][1] = *reinterpret_cast<const sh8*>(
                &Ks[cur][(rk * 64 + 32 + g * 8) ^ ((rk & 7) << 3)]);
        }
        #pragma unroll
        for (int nf = 0; nf < 4; nf++) {
            int rv = nf * 16 + tx;
            vf[nf] = *reinterpret_cast<const sh8*>(
                &Vs[cur][(rv * 64 + 32 * kw + g * 8) ^ ((rv & 7) << 3)]);
        }
        #pragma unroll
        for (int qg = 0; qg < 4; qg++) {
            f4 sa = {}, sb = {};
            sa = MFMA(kf[0][0], qf[qg][0], sa); sa = MFMA(kf[0][1], qf[qg][1], sa);
            sb = MFMA(kf[1][0], qf[qg][0], sb); sb = MFMA(kf[1][1], qf[qg][1], sb);
            sh8 pf = packP(sa, sb);            // tau-slots 32kw + 8g + 4nf' + i
            #pragma unroll
            for (int nf = 0; nf < 4; nf++)
                o[qg][nf] = MFMA(vf[nf], pf, o[qg][nf]);
            ol[qg] = MFMA(onesf, pf, ol[qg]);
        }
    };

    stage(0); advance(0);
    asm volatile("s_waitcnt vmcnt(0)" ::: "memory");
    __builtin_amdgcn_s_barrier();
    __builtin_amdgcn_sched_barrier(0);
    int cur = 0;

    for (int t = 0; t < Lv / 64 - 1; t++) {
        stage(cur ^ 1); advance(t + 1);    // 4 loads fly across the barrier
        asm volatile("s_waitcnt vmcnt(4)" ::: "memory");   // tile-t loads landed
        __builtin_amdgcn_s_barrier();
        __builtin_amdgcn_sched_barrier(0);
        compute(cur);
        __builtin_amdgcn_sched_barrier(0);
        __builtin_amdgcn_s_barrier();      // all reads of cur done before overwrite
        cur ^= 1;
    }
    asm volatile("s_waitcnt vmcnt(0)" ::: "memory");       // last tile resident
    __builtin_amdgcn_s_barrier();
    __builtin_amdgcn_sched_barrier(0);
    compute(cur);

    // cross-wave (kw) reduction: kw=1 writes partials to dead Ks/Vs, kw=0 adds
    float* ex = qw ? reinterpret_cast<float*>(Vs) : reinterpret_cast<float*>(Ks);
    if (kw) {
        #pragma unroll
        for (int qg = 0; qg < 4; qg++) {
            #pragma unroll
            for (int nf = 0; nf < 4; nf++)
                *reinterpret_cast<f4*>(&ex[((qg * 4 + nf) * 64 + lane) * 4]) = o[qg][nf];
            olex[qw][qg][lane] = ol[qg][0];
        }
    }
    __syncthreads();
    if (!kw) {
        #pragma unroll
        for (int qg = 0; qg < 4; qg++) {
            float l = ol[qg][0] + olex[qw][qg][lane];
            float inv = 1.0f / l;
            size_t ybase = ((size_t)(b * Tv) + qt * 128 + qw * 64 + qg * 16 + tx) * Dv + h * 64;
            #pragma unroll
            for (int nf = 0; nf < 4; nf++) {
                f4 op = o[qg][nf] +
                    *reinterpret_cast<const f4*>(&ex[((qg * 4 + nf) * 64 + lane) * 4]);
                sh4 ph;
                #pragma unroll
                for (int i = 0; i < 4; i++) ph[i] = (short)bf16_rn(op[i] * inv);
                *reinterpret_cast<sh4*>(&yh[ybase + nf * 16 + g * 4]) = ph;
            }
        }
    }
}

// ---------------------------------------------------------------------------
// Kernel 3: out = y @ Wo^T, fp32 out.  SINGLE bf16 segment, K=1024 (16 steps)
// -- the 3-term split was overkill: sigma(y)~0.014 makes bf16 error ~2e-5 at
// the output.  64x128 tile, (64,8) grid, single-buffered 24KB LDS.
// ---------------------------------------------------------------------------
__global__ __launch_bounds__(256) void out_gemm(
    const unsigned short* __restrict__ yh,
    const unsigned short* __restrict__ woh,
    float* __restrict__ out)
{
    __shared__ __align__(16) unsigned short As[64 * 64], Bs[128 * 64];
    const int tid = threadIdx.x;
    const int lane = tid & 63, w = tid >> 6;
    const int g = lane >> 4, tx = lane & 15;
    const int wr = w >> 1, wc = w & 1;
    const int m0 = blockIdx.x * 64, n0 = blockIdx.y * 128;
    const int srow = lane >> 3, scol = lane & 7;

    f4 acc[2][4] = {};

    for (int k0 = 0; k0 < Dv; k0 += 64) {
        #pragma unroll
        for (int c = 0; c < 2; c++) {
            int row = w * 16 + c * 8 + srow;
            int su = (scol ^ (row & 7)) << 3;
            gload16(&yh[(size_t)(m0 + row) * Dv + k0 + su], &As[(w * 16 + c * 8) * 64]);
        }
        #pragma unroll
        for (int c = 0; c < 4; c++) {
            int row = w * 32 + c * 8 + srow;
            int su = (scol ^ (row & 7)) << 3;
            gload16(&woh[(size_t)(n0 + row) * Dv + k0 + su], &Bs[(w * 32 + c * 8) * 64]);
        }
        __syncthreads();
        #pragma unroll
        for (int ks = 0; ks < 2; ks++) {
            sh8 fa[2], fb[4];
            #pragma unroll
            for (int mi = 0; mi < 2; mi++) {
                int r = wr * 32 + mi * 16 + tx;
                fa[mi] = *reinterpret_cast<const sh8*>(&As[(r * 64 + ks * 32 + g * 8) ^ ((r & 7) << 3)]);
            }
            #pragma unroll
            for (int ni = 0; ni < 4; ni++) {
                int r = wc * 64 + ni * 16 + tx;
                fb[ni] = *reinterpret_cast<const sh8*>(&Bs[(r * 64 + ks * 32 + g * 8) ^ ((r & 7) << 3)]);
            }
            #pragma unroll
            for (int mi = 0; mi < 2; mi++)
                #pragma unroll
                for (int ni = 0; ni < 4; ni++)
                    acc[mi][ni] = MFMA(fb[ni], fa[mi], acc[mi][ni]);   // C: row=n, col=m
        }
        __syncthreads();
    }

    #pragma unroll
    for (int mi = 0; mi < 2; mi++)
        #pragma unroll
        for (int ni = 0; ni < 4; ni++) {
            int m = m0 + wr * 32 + mi * 16 + tx;
            int n = n0 + wc * 64 + ni * 16 + g * 4;
            *reinterpret_cast<float4*>(&out[(size_t)m * Dv + n]) =
                make_float4(acc[mi][ni][0], acc[mi][ni][1], acc[mi][ni][2], acc[mi][ni][3]);
        }
}

// ---------------------------------------------------------------------------
extern "C" void kernel_launch(void* const* d_in, const int* in_sizes, int n_in,
                              void* d_out, int out_size, void* d_ws, size_t ws_size,
                              hipStream_t stream)
{
    const float* x  = (const float*)d_in[0];
    const float* pk = (const float*)d_in[1];
    const float* pv = (const float*)d_in[2];
    const float* Wq = (const float*)d_in[3];
    const float* Wk = (const float*)d_in[4];
    const float* Wv = (const float*)d_in[5];
    const float* Wo = (const float*)d_in[6];

    const size_t M1 = 1048576;
    unsigned short* ws  = (unsigned short*)d_ws;   // 24M ushorts = 48 MB
    unsigned short* xb   = ws;                     // 4M  [B*T, D]
    unsigned short* wqb  = ws + 4  * M1;           // 1M
    unsigned short* wkb  = ws + 5  * M1;
    unsigned short* wvb  = ws + 6  * M1;
    unsigned short* woh  = ws + 7  * M1;
    unsigned short* pkb  = ws + 8  * M1;           // [B,H,P,DH]
    unsigned short* pvtb = ws + 9  * M1;           // [B,H,DH,P] tau-permuted keys
    unsigned short* qb   = ws + 10 * M1;           // 4M [B,T,D] (pre-scaled by C)
    unsigned short* kb   = ws + 14 * M1;           // 4M [B,T,D]
    unsigned short* vtb  = ws + 18 * M1;           // 4M [B,H,DH,T] tau-permuted keys
    unsigned short* yh   = ws + 22 * M1;           // 4M [B,T,D]

    prep_convert<<<9216, 256, 0, stream>>>(x, Wq, Wk, Wv, pk, Wo,
                                           xb, wqb, wkb, wvb, pkb, woh);
    prep_transpose<<<256, 256, 0, stream>>>(pv, pvtb);
    qkv_gemm<<<dim3(32, 8, 3), 256, 0, stream>>>(xb, wqb, wkb, wvb, qb, kb, vtb);
    flash_mfma<<<dim3(Bv * Hv * (Tv / 128)), 256, 0, stream>>>(qb, kb, vtb, pkb, pvtb, yh);
    out_gemm<<<dim3(64, 8), 256, 0, stream>>>(yh, woh, (float*)d_out);
}

// Round 12
// 120.910 us; speedup vs baseline: 1.4989x; 1.0007x over previous
//
#include <hip/hip_runtime.h>
#include <cstdint>

#define Bv  2
#define Tv  2048
#define Dv  1024
#define Hv  16
#define DHv 64
#define Pv  512
#define Lv  2560   // P + T
#define NT  (Lv / 64)   // 40 key tiles

typedef __attribute__((ext_vector_type(8))) short sh8;   // 8 bf16 MFMA frag
typedef __attribute__((ext_vector_type(4))) short sh4;
typedef __attribute__((ext_vector_type(4))) float f4;
typedef __attribute__((ext_vector_type(4))) unsigned int u4v;

#define MFMA(a,b,c) __builtin_amdgcn_mfma_f32_16x16x32_bf16(a,b,c,0,0,0)

__device__ __forceinline__ unsigned short bf16_rn(float f) {
    unsigned int u = __builtin_bit_cast(unsigned int, f);
    u += 0x7FFFu + ((u >> 16) & 1u);          // RTNE
    return (unsigned short)(u >> 16);
}
__device__ __forceinline__ float bf16_f(unsigned short h) {
    unsigned int u = ((unsigned int)h) << 16;
    return __builtin_bit_cast(float, u);
}
__device__ __forceinline__ unsigned int fbits(float f) {
    return __builtin_bit_cast(unsigned int, f);
}

// async global->LDS, 16B per lane; LDS dest = wave-uniform base + lane*16
__device__ __forceinline__ void gload16(const unsigned short* g, unsigned short* l) {
    __builtin_amdgcn_global_load_lds(
        (const __attribute__((address_space(1))) unsigned int*)(g),
        (__attribute__((address_space(3))) unsigned int*)(l),
        16, 0, 0);
}

// exp2 + truncate-pack two QK accumulators (8 P values) into one bf16 B-frag.
__device__ __forceinline__ sh8 packP(const f4 a, const f4 b) {
    float e0 = __builtin_amdgcn_exp2f(a[0]), e1 = __builtin_amdgcn_exp2f(a[1]);
    float e2 = __builtin_amdgcn_exp2f(a[2]), e3 = __builtin_amdgcn_exp2f(a[3]);
    float f0 = __builtin_amdgcn_exp2f(b[0]), f1 = __builtin_amdgcn_exp2f(b[1]);
    float f2 = __builtin_amdgcn_exp2f(b[2]), f3 = __builtin_amdgcn_exp2f(b[3]);
    u4v d;
    d[0] = __builtin_amdgcn_perm(fbits(e1), fbits(e0), 0x07060302u);
    d[1] = __builtin_amdgcn_perm(fbits(e3), fbits(e2), 0x07060302u);
    d[2] = __builtin_amdgcn_perm(fbits(f1), fbits(f0), 0x07060302u);
    d[3] = __builtin_amdgcn_perm(fbits(f3), fbits(f2), 0x07060302u);
    return __builtin_bit_cast(sh8, d);
}

// ---------------------------------------------------------------------------
// Prep (merged): blocks [0,9216) = fp32->bf16 conversions (x,Wq,Wk,Wv,pk,Wo);
// blocks [9216,9472) = pv transpose to [B,H,DH,P'] with tau-permuted keys.
// tau: run u (keys 8u+j): slot(j<4) = 32*((u>>2)&1)+16*(u&1)+4*((u>>1)&1)+j,
// slot(j>=4) = that + 8.
// ---------------------------------------------------------------------------
__global__ __launch_bounds__(256) void prep_all(
    const float* __restrict__ x,  const float* __restrict__ Wq,
    const float* __restrict__ Wk, const float* __restrict__ Wv,
    const float* __restrict__ pk, const float* __restrict__ Wo,
    const float* __restrict__ pv,
    unsigned short* __restrict__ xb,  unsigned short* __restrict__ wqb,
    unsigned short* __restrict__ wkb, unsigned short* __restrict__ wvb,
    unsigned short* __restrict__ pkb, unsigned short* __restrict__ woh,
    unsigned short* __restrict__ pvtb)
{
    __shared__ unsigned short Tls[64][66];
    const int blk = blockIdx.x;
    const int tid = threadIdx.x;
    if (blk < 9216) {
        int i = blk * 256 + tid;              // float4 index, total 2359296
        const float* src; unsigned short* dst; int off;
        if      (i < 1048576) { src = x;  dst = xb;  off = i; }
        else if (i < 1310720) { src = Wq; dst = wqb; off = i - 1048576; }
        else if (i < 1572864) { src = Wk; dst = wkb; off = i - 1310720; }
        else if (i < 1835008) { src = Wv; dst = wvb; off = i - 1572864; }
        else if (i < 2097152) { src = pk; dst = pkb; off = i - 1835008; }
        else                  { src = Wo; dst = woh; off = i - 2097152; }
        float4 v = reinterpret_cast<const float4*>(src)[off];
        sh4 h;
        h[0] = (short)bf16_rn(v.x); h[1] = (short)bf16_rn(v.y);
        h[2] = (short)bf16_rn(v.z); h[3] = (short)bf16_rn(v.w);
        reinterpret_cast<sh4*>(dst)[off] = h;
    } else {
        const int bb = blk - 9216;            // 0..255
        const int bh = bb >> 3, pt = bb & 7;
        #pragma unroll
        for (int i = 0; i < 4; i++) {
            int id = i * 256 + tid;
            int p = id >> 4, c4 = (id & 15) << 2;
            float4 v = *reinterpret_cast<const float4*>(
                &pv[((size_t)bh * Pv + pt * 64 + p) * DHv + c4]);
            Tls[c4+0][p] = bf16_rn(v.x);
            Tls[c4+1][p] = bf16_rn(v.y);
            Tls[c4+2][p] = bf16_rn(v.z);
            Tls[c4+3][p] = bf16_rn(v.w);
        }
        __syncthreads();
        #pragma unroll
        for (int i = 0; i < 2; i++) {
            int id = i * 256 + tid;
            int d = id >> 3, u = id & 7;      // dh row, 8-key run index
            sh4 lo, hi;
            #pragma unroll
            for (int j = 0; j < 4; j++) {
                lo[j] = (short)Tls[d][u * 8 + j];
                hi[j] = (short)Tls[d][u * 8 + 4 + j];
            }
            int p0 = ((u >> 2) & 1) * 32 + (u & 1) * 16 + ((u >> 1) & 1) * 4;
            size_t base = ((size_t)bh * DHv + d) * Pv + pt * 64;
            *reinterpret_cast<sh4*>(&pvtb[base + p0])     = lo;
            *reinterpret_cast<sh4*>(&pvtb[base + p0 + 8]) = hi;
        }
    }
}

// ---------------------------------------------------------------------------
// Kernel 1: QKV projection, single-bf16 MFMA, m97 structure (single-buffered).
// Q pre-scaled by 0.125*log2(e); V^T stored tau-permuted per 64-tile.
// ---------------------------------------------------------------------------
__global__ __launch_bounds__(256) void qkv_gemm(
    const unsigned short* __restrict__ xb,
    const unsigned short* __restrict__ wqb, const unsigned short* __restrict__ wkb,
    const unsigned short* __restrict__ wvb,
    unsigned short* __restrict__ qb, unsigned short* __restrict__ kb,
    unsigned short* __restrict__ vtb)
{
    __shared__ __align__(16) unsigned short As[128 * 64], Bs[128 * 64];
    const int tid = threadIdx.x;
    const int lane = tid & 63, w = tid >> 6;
    const int g = lane >> 4, tx = lane & 15;
    const int wr = w >> 1, wc = w & 1;
    const int m0 = blockIdx.x * 128, n0 = blockIdx.y * 128;
    const int z = blockIdx.z;
    const unsigned short* Wb = (z == 0) ? wqb : (z == 1) ? wkb : wvb;
    const int srow = lane >> 3, scol = lane & 7;

    f4 acc[4][4] = {};

    for (int k0 = 0; k0 < Dv; k0 += 64) {
        #pragma unroll
        for (int c = 0; c < 4; c++) {
            int row = w * 32 + c * 8 + srow;
            int su = (scol ^ (row & 7)) << 3;
            gload16(&xb[(size_t)(m0 + row) * Dv + k0 + su], &As[(w * 32 + c * 8) * 64]);
            gload16(&Wb[(size_t)(n0 + row) * Dv + k0 + su], &Bs[(w * 32 + c * 8) * 64]);
        }
        __syncthreads();
        #pragma unroll
        for (int ks = 0; ks < 2; ks++) {
            sh8 fa[4], fb[4];
            #pragma unroll
            for (int mi = 0; mi < 4; mi++) {
                int r = wr * 64 + mi * 16 + tx;
                fa[mi] = *reinterpret_cast<const sh8*>(&As[(r * 64 + ks * 32 + g * 8) ^ ((r & 7) << 3)]);
            }
            #pragma unroll
            for (int ni = 0; ni < 4; ni++) {
                int r = wc * 64 + ni * 16 + tx;
                fb[ni] = *reinterpret_cast<const sh8*>(&Bs[(r * 64 + ks * 32 + g * 8) ^ ((r & 7) << 3)]);
            }
            if (z < 2) {
                #pragma unroll
                for (int mi = 0; mi < 4; mi++)
                    #pragma unroll
                    for (int ni = 0; ni < 4; ni++)
                        acc[mi][ni] = MFMA(fb[ni], fa[mi], acc[mi][ni]);   // C: row=n, col=m
            } else {
                #pragma unroll
                for (int mi = 0; mi < 4; mi++)
                    #pragma unroll
                    for (int ni = 0; ni < 4; ni++)
                        acc[mi][ni] = MFMA(fa[mi], fb[ni], acc[mi][ni]);   // C: row=m, col=n
            }
        }
        __syncthreads();
    }

    if (z < 2) {
        unsigned short* ob = (z == 0) ? qb : kb;
        const float sc = (z == 0) ? 0.1803368801f : 1.0f;   // 0.125*log2(e) into Q
        #pragma unroll
        for (int mi = 0; mi < 4; mi++)
            #pragma unroll
            for (int ni = 0; ni < 4; ni++) {
                int m = m0 + wr * 64 + mi * 16 + tx;          // col of C = x row
                int n = n0 + wc * 64 + ni * 16 + g * 4;       // row of C = W row (base)
                sh4 pkd;
                #pragma unroll
                for (int i = 0; i < 4; i++) pkd[i] = (short)bf16_rn(acc[mi][ni][i] * sc);
                *reinterpret_cast<sh4*>(&ob[(size_t)m * Dv + n]) = pkd;
            }
    } else {
        const int tb0 = ((m0 + wr * 64) & (Tv - 1));          // 64-aligned t-block
        const int b   = (m0 + wr * 64) >> 11;
        #pragma unroll
        for (int mi = 0; mi < 4; mi++)
            #pragma unroll
            for (int ni = 0; ni < 4; ni++) {
                // key = mi*16 + g*4 + i  ->  tau-slot = 32*(mi>>1) + 8g + 4*(mi&1) + i
                int t = tb0 + ((mi & 2) << 4) + (g << 3) + ((mi & 1) << 2);
                int n = n0 + wc * 64 + ni * 16 + tx;          // col of C = W row
                int h = n >> 6, dh = n & 63;
                sh4 pkd;
                #pragma unroll
                for (int i = 0; i < 4; i++) pkd[i] = (short)bf16_rn(acc[mi][ni][i]);
                *reinterpret_cast<sh4*>(&vtb[(((size_t)(b * Hv + h)) * DHv + dh) * Tv + t]) = pkd;
            }
    }
}

// ---------------------------------------------------------------------------
// Kernel 2: flash attention.  KEY-SPLIT + 3-BUFFER SINGLE-BARRIER PIPELINE:
// per tile: wait vmcnt(4) -> ONE s_barrier -> stage((t+2)%3) -> compute(t%3).
// 3 buffers make the 2nd (anti-overwrite) barrier redundant: stage target at
// iter t was last computed at t-1, and every wave provably finished that
// before passing iter-t's barrier.  Each tile's loads get a full compute
// phase (~3000cyc >> HBM latency) to land.  40 barriers total (was 80).
// tau key-relabel keeps P in registers; no-max softmax; l via ones-MFMA.
// LDS 50KB.
// ---------------------------------------------------------------------------
__global__ __launch_bounds__(256) void flash_mfma(
    const unsigned short* __restrict__ qbuf, const unsigned short* __restrict__ kb,
    const unsigned short* __restrict__ vtb,
    const unsigned short* __restrict__ pkb, const unsigned short* __restrict__ pvtb,
    unsigned short* __restrict__ yh)
{
    __shared__ __align__(16) unsigned short Ks[3][64 * 64], Vs[3][64 * 64];
    __shared__ float olex[2][4][64];
    const int tid = threadIdx.x;
    const int lane = tid & 63, w = tid >> 6;       // 4 waves
    const int kw = w & 1, qw = w >> 1;             // key-half, q-half
    const int g = lane >> 4, tx = lane & 15;
    // XCD swizzle: 512 blocks, 8 XCDs, chunk=64 => 4 bh per XCD
    const int pblk = blockIdx.x;
    const int L = (pblk & 7) * 64 + (pblk >> 3);
    const int qt = L & 15;                 // 16 q-tiles of 128 rows
    const int bh = L >> 4;
    const int b = bh >> 4, h = bh & 15;
    const int srow = lane >> 3, scol = lane & 7;

    // Q frags: 4 groups x 2 dh-halves (MFMA B-operand, pre-scaled)
    sh8 qf[4][2];
    #pragma unroll
    for (int qg = 0; qg < 4; qg++) {
        size_t base = ((size_t)(b * Tv) + qt * 128 + qw * 64 + qg * 16 + tx) * Dv + h * 64;
        qf[qg][0] = *reinterpret_cast<const sh8*>(&qbuf[base + g * 8]);
        qf[qg][1] = *reinterpret_cast<const sh8*>(&qbuf[base + 32 + g * 8]);
    }

    f4 o[4][4] = {};          // [q-group][dh-frag], partial over this wave's keys
    f4 ol[4] = {};            // ones-colsum accumulators (partial l per group)
    sh8 onesf;
    #pragma unroll
    for (int j = 0; j < 8; j++) onesf[j] = (short)0x3F80;   // bf16 1.0

    // staging pointers (wave stages rows w*16..+15 of both K and V tiles)
    const int r0 = w * 16 + srow, r1 = r0 + 8;
    const int su0 = (scol ^ (r0 & 7)) << 3;
    const int su1 = (scol ^ (r1 & 7)) << 3;
    const unsigned short* ka0 = &pkb[((size_t)bh * Pv + r0) * DHv + su0];
    const unsigned short* ka1 = &pkb[((size_t)bh * Pv + r1) * DHv + su1];
    const unsigned short* va0 = &pvtb[((size_t)bh * DHv + r0) * Pv + su0];
    const unsigned short* va1 = &pvtb[((size_t)bh * DHv + r1) * Pv + su1];

    auto stage = [&](int buf) {            // 4 gload16 per wave per tile
        gload16(ka0, &Ks[buf][(w * 16    ) * 64]);
        gload16(ka1, &Ks[buf][(w * 16 + 8) * 64]);
        gload16(va0, &Vs[buf][(w * 16    ) * 64]);
        gload16(va1, &Vs[buf][(w * 16 + 8) * 64]);
    };
    auto advance = [&](int nt) {           // nt = tile just staged
        if (nt == 7) {                     // switch prefix -> computed arrays
            ka0 = &kb[((size_t)(b * Tv) + r0) * Dv + h * 64 + su0];
            ka1 = &kb[((size_t)(b * Tv) + r1) * Dv + h * 64 + su1];
            va0 = &vtb[((size_t)bh * DHv + r0) * Tv + su0];
            va1 = &vtb[((size_t)bh * DHv + r1) * Tv + su1];
        } else if (nt < 7) { ka0 += 64 * DHv; ka1 += 64 * DHv; va0 += 64; va1 += 64; }
        else               { ka0 += 64 * Dv;  ka1 += 64 * Dv;  va0 += 64; va1 += 64; }
    };

    auto compute = [&](int cur) {
        // this wave's half of K (2 nf x 2 dh-halves) and V (4 nf x 32-key cols)
        sh8 kf[2][2], vf[4];
        #pragma unroll
        for (int nf = 0; nf < 2; nf++) {
            int rk = 32 * kw + nf * 16 + tx;
            kf[nf][0] = *reinterpret_cast<const sh8*>(
                &Ks[cur][(rk * 64 + g * 8) ^ ((rk & 7) << 3)]);
            kf[nf][1] = *reinterpret_cast<const sh8*>(
                &Ks[cur][(rk * 64 + 32 + g * 8) ^ ((rk & 7) << 3)]);
        }
        #pragma unroll
        for (int nf = 0; nf < 4; nf++) {
            int rv = nf * 16 + tx;
            vf[nf] = *reinterpret_cast<const sh8*>(
                &Vs[cur][(rv * 64 + 32 * kw + g * 8) ^ ((rv & 7) << 3)]);
        }
        #pragma unroll
        for (int qg = 0; qg < 4; qg++) {
            f4 sa = {}, sb = {};
            sa = MFMA(kf[0][0], qf[qg][0], sa); sa = MFMA(kf[0][1], qf[qg][1], sa);
            sb = MFMA(kf[1][0], qf[qg][0], sb); sb = MFMA(kf[1][1], qf[qg][1], sb);
            sh8 pf = packP(sa, sb);            // tau-slots 32kw + 8g + 4nf' + i
            #pragma unroll
            for (int nf = 0; nf < 4; nf++)
                o[qg][nf] = MFMA(vf[nf], pf, o[qg][nf]);
            ol[qg] = MFMA(onesf, pf, ol[qg]);
        }
    };

    stage(0); advance(0);
    stage(1); advance(1);                  // 8 loads in flight
    int cur = 0, stg = 2;

    #pragma unroll 1
    for (int t = 0; t < NT - 2; t++) {
        asm volatile("s_waitcnt vmcnt(4)" ::: "memory");   // tile t landed; t+1 flying
        __builtin_amdgcn_s_barrier();
        __builtin_amdgcn_sched_barrier(0);
        stage(stg); advance(t + 2);        // overwrite target: computed at t-1, safe
        compute(cur);
        __builtin_amdgcn_sched_barrier(0);
        cur = (cur == 2) ? 0 : cur + 1;
        stg = (stg == 2) ? 0 : stg + 1;
    }
    asm volatile("s_waitcnt vmcnt(4)" ::: "memory");       // tile NT-2 landed
    __builtin_amdgcn_s_barrier();
    __builtin_amdgcn_sched_barrier(0);
    compute(cur);
    __builtin_amdgcn_sched_barrier(0);
    cur = (cur == 2) ? 0 : cur + 1;
    asm volatile("s_waitcnt vmcnt(0)" ::: "memory");       // tile NT-1 landed
    __builtin_amdgcn_s_barrier();
    __builtin_amdgcn_sched_barrier(0);
    compute(cur);

    // cross-wave (kw) reduction: kw=1 writes partials to dead Ks/Vs, kw=0 adds
    float* ex = qw ? reinterpret_cast<float*>(Vs) : reinterpret_cast<float*>(Ks);
    if (kw) {
        #pragma unroll
        for (int qg = 0; qg < 4; qg++) {
            #pragma unroll
            for (int nf = 0; nf < 4; nf++)
                *reinterpret_cast<f4*>(&ex[((qg * 4 + nf) * 64 + lane) * 4]) = o[qg][nf];
            olex[qw][qg][lane] = ol[qg][0];
        }
    }
    __syncthreads();
    if (!kw) {
        #pragma unroll
        for (int qg = 0; qg < 4; qg++) {
            float l = ol[qg][0] + olex[qw][qg][lane];
            float inv = 1.0f / l;
            size_t ybase = ((size_t)(b * Tv) + qt * 128 + qw * 64 + qg * 16 + tx) * Dv + h * 64;
            #pragma unroll
            for (int nf = 0; nf < 4; nf++) {
                f4 op = o[qg][nf] +
                    *reinterpret_cast<const f4*>(&ex[((qg * 4 + nf) * 64 + lane) * 4]);
                sh4 ph;
                #pragma unroll
                for (int i = 0; i < 4; i++) ph[i] = (short)bf16_rn(op[i] * inv);
                *reinterpret_cast<sh4*>(&yh[ybase + nf * 16 + g * 4]) = ph;
            }
        }
    }
}

// ---------------------------------------------------------------------------
// Kernel 3: out = y @ Wo^T, fp32 out.  Single bf16 segment, K=1024 (16 steps).
// 64x128 tile, (64,8) grid, single-buffered 24KB LDS.
// ---------------------------------------------------------------------------
__global__ __launch_bounds__(256) void out_gemm(
    const unsigned short* __restrict__ yh,
    const unsigned short* __restrict__ woh,
    float* __restrict__ out)
{
    __shared__ __align__(16) unsigned short As[64 * 64], Bs[128 * 64];
    const int tid = threadIdx.x;
    const int lane = tid & 63, w = tid >> 6;
    const int g = lane >> 4, tx = lane & 15;
    const int wr = w >> 1, wc = w & 1;
    const int m0 = blockIdx.x * 64, n0 = blockIdx.y * 128;
    const int srow = lane >> 3, scol = lane & 7;

    f4 acc[2][4] = {};

    for (int k0 = 0; k0 < Dv; k0 += 64) {
        #pragma unroll
        for (int c = 0; c < 2; c++) {
            int row = w * 16 + c * 8 + srow;
            int su = (scol ^ (row & 7)) << 3;
            gload16(&yh[(size_t)(m0 + row) * Dv + k0 + su], &As[(w * 16 + c * 8) * 64]);
        }
        #pragma unroll
        for (int c = 0; c < 4; c++) {
            int row = w * 32 + c * 8 + srow;
            int su = (scol ^ (row & 7)) << 3;
            gload16(&woh[(size_t)(n0 + row) * Dv + k0 + su], &Bs[(w * 32 + c * 8) * 64]);
        }
        __syncthreads();
        #pragma unroll
        for (int ks = 0; ks < 2; ks++) {
            sh8 fa[2], fb[4];
            #pragma unroll
            for (int mi = 0; mi < 2; mi++) {
                int r = wr * 32 + mi * 16 + tx;
                fa[mi] = *reinterpret_cast<const sh8*>(&As[(r * 64 + ks * 32 + g * 8) ^ ((r & 7) << 3)]);
            }
            #pragma unroll
            for (int ni = 0; ni < 4; ni++) {
                int r = wc * 64 + ni * 16 + tx;
                fb[ni] = *reinterpret_cast<const sh8*>(&Bs[(r * 64 + ks * 32 + g * 8) ^ ((r & 7) << 3)]);
            }
            #pragma unroll
            for (int mi = 0; mi < 2; mi++)
                #pragma unroll
                for (int ni = 0; ni < 4; ni++)
                    acc[mi][ni] = MFMA(fb[ni], fa[mi], acc[mi][ni]);   // C: row=n, col=m
        }
        __syncthreads();
    }

    #pragma unroll
    for (int mi = 0; mi < 2; mi++)
        #pragma unroll
        for (int ni = 0; ni < 4; ni++) {
            int m = m0 + wr * 32 + mi * 16 + tx;
            int n = n0 + wc * 64 + ni * 16 + g * 4;
            *reinterpret_cast<float4*>(&out[(size_t)m * Dv + n]) =
                make_float4(acc[mi][ni][0], acc[mi][ni][1], acc[mi][ni][2], acc[mi][ni][3]);
        }
}

// ---------------------------------------------------------------------------
extern "C" void kernel_launch(void* const* d_in, const int* in_sizes, int n_in,
                              void* d_out, int out_size, void* d_ws, size_t ws_size,
                              hipStream_t stream)
{
    const float* x  = (const float*)d_in[0];
    const float* pk = (const float*)d_in[1];
    const float* pv = (const float*)d_in[2];
    const float* Wq = (const float*)d_in[3];
    const float* Wk = (const float*)d_in[4];
    const float* Wv = (const float*)d_in[5];
    const float* Wo = (const float*)d_in[6];

    const size_t M1 = 1048576;
    unsigned short* ws  = (unsigned short*)d_ws;   // 23M ushorts = 46 MB
    unsigned short* xb   = ws;                     // 4M  [B*T, D]
    unsigned short* wqb  = ws + 4  * M1;           // 1M
    unsigned short* wkb  = ws + 5  * M1;
    unsigned short* wvb  = ws + 6  * M1;
    unsigned short* woh  = ws + 7  * M1;
    unsigned short* pkb  = ws + 8  * M1;           // [B,H,P,DH]
    unsigned short* pvtb = ws + 9  * M1;           // [B,H,DH,P] tau-permuted keys
    unsigned short* qb   = ws + 10 * M1;           // 4M [B,T,D] (pre-scaled by C)
    unsigned short* kb   = ws + 14 * M1;           // 4M [B,T,D]
    unsigned short* vtb  = ws + 18 * M1;           // 4M [B,H,DH,T] tau-permuted keys
    unsigned short* yh   = ws + 22 * M1;           // 4M [B,T,D]

    prep_all<<<9472, 256, 0, stream>>>(x, Wq, Wk, Wv, pk, Wo, pv,
                                       xb, wqb, wkb, wvb, pkb, woh, pvtb);
    qkv_gemm<<<dim3(32, 8, 3), 256, 0, stream>>>(xb, wqb, wkb, wvb, qb, kb, vtb);
    flash_mfma<<<dim3(Bv * Hv * (Tv / 128)), 256, 0, stream>>>(qb, kb, vtb, pkb, pvtb, yh);
    out_gemm<<<dim3(64, 8), 256, 0, stream>>>(yh, woh, (float*)d_out);
}

// Round 13
// 120.707 us; speedup vs baseline: 1.5014x; 1.0017x over previous
//
#include <hip/hip_runtime.h>
#include <cstdint>

#define Bv  2
#define Tv  2048
#define Dv  1024
#define Hv  16
#define DHv 64
#define Pv  512
#define Lv  2560   // P + T
#define NT  (Lv / 64)   // 40 key tiles

typedef __attribute__((ext_vector_type(8))) short sh8;   // 8 bf16 MFMA frag
typedef __attribute__((ext_vector_type(4))) short sh4;
typedef __attribute__((ext_vector_type(4))) float f4;
typedef __attribute__((ext_vector_type(4))) unsigned int u4v;

#define MFMA(a,b,c) __builtin_amdgcn_mfma_f32_16x16x32_bf16(a,b,c,0,0,0)

__device__ __forceinline__ unsigned short bf16_rn(float f) {
    unsigned int u = __builtin_bit_cast(unsigned int, f);
    u += 0x7FFFu + ((u >> 16) & 1u);          // RTNE
    return (unsigned short)(u >> 16);
}
__device__ __forceinline__ float bf16_f(unsigned short h) {
    unsigned int u = ((unsigned int)h) << 16;
    return __builtin_bit_cast(float, u);
}
__device__ __forceinline__ unsigned int fbits(float f) {
    return __builtin_bit_cast(unsigned int, f);
}

// async global->LDS, 16B per lane; LDS dest = wave-uniform base + lane*16
__device__ __forceinline__ void gload16(const unsigned short* g, unsigned short* l) {
    __builtin_amdgcn_global_load_lds(
        (const __attribute__((address_space(1))) unsigned int*)(g),
        (__attribute__((address_space(3))) unsigned int*)(l),
        16, 0, 0);
}

// exp2 + truncate-pack two QK accumulators (8 P values) into one bf16 B-frag.
__device__ __forceinline__ sh8 packP(const f4 a, const f4 b) {
    float e0 = __builtin_amdgcn_exp2f(a[0]), e1 = __builtin_amdgcn_exp2f(a[1]);
    float e2 = __builtin_amdgcn_exp2f(a[2]), e3 = __builtin_amdgcn_exp2f(a[3]);
    float f0 = __builtin_amdgcn_exp2f(b[0]), f1 = __builtin_amdgcn_exp2f(b[1]);
    float f2 = __builtin_amdgcn_exp2f(b[2]), f3 = __builtin_amdgcn_exp2f(b[3]);
    u4v d;
    d[0] = __builtin_amdgcn_perm(fbits(e1), fbits(e0), 0x07060302u);
    d[1] = __builtin_amdgcn_perm(fbits(e3), fbits(e2), 0x07060302u);
    d[2] = __builtin_amdgcn_perm(fbits(f1), fbits(f0), 0x07060302u);
    d[3] = __builtin_amdgcn_perm(fbits(f3), fbits(f2), 0x07060302u);
    return __builtin_bit_cast(sh8, d);
}

// ---------------------------------------------------------------------------
// Prep (merged): blocks [0,9216) = fp32->bf16 conversions (x,Wq,Wk,Wv,pk,Wo);
// blocks [9216,9472) = pv transpose to [B,H,DH,P'] with tau-permuted keys.
// ---------------------------------------------------------------------------
__global__ __launch_bounds__(256) void prep_all(
    const float* __restrict__ x,  const float* __restrict__ Wq,
    const float* __restrict__ Wk, const float* __restrict__ Wv,
    const float* __restrict__ pk, const float* __restrict__ Wo,
    const float* __restrict__ pv,
    unsigned short* __restrict__ xb,  unsigned short* __restrict__ wqb,
    unsigned short* __restrict__ wkb, unsigned short* __restrict__ wvb,
    unsigned short* __restrict__ pkb, unsigned short* __restrict__ woh,
    unsigned short* __restrict__ pvtb)
{
    __shared__ unsigned short Tls[64][66];
    const int blk = blockIdx.x;
    const int tid = threadIdx.x;
    if (blk < 9216) {
        int i = blk * 256 + tid;              // float4 index, total 2359296
        const float* src; unsigned short* dst; int off;
        if      (i < 1048576) { src = x;  dst = xb;  off = i; }
        else if (i < 1310720) { src = Wq; dst = wqb; off = i - 1048576; }
        else if (i < 1572864) { src = Wk; dst = wkb; off = i - 1310720; }
        else if (i < 1835008) { src = Wv; dst = wvb; off = i - 1572864; }
        else if (i < 2097152) { src = pk; dst = pkb; off = i - 1835008; }
        else                  { src = Wo; dst = woh; off = i - 2097152; }
        float4 v = reinterpret_cast<const float4*>(src)[off];
        sh4 h;
        h[0] = (short)bf16_rn(v.x); h[1] = (short)bf16_rn(v.y);
        h[2] = (short)bf16_rn(v.z); h[3] = (short)bf16_rn(v.w);
        reinterpret_cast<sh4*>(dst)[off] = h;
    } else {
        const int bb = blk - 9216;            // 0..255
        const int bh = bb >> 3, pt = bb & 7;
        #pragma unroll
        for (int i = 0; i < 4; i++) {
            int id = i * 256 + tid;
            int p = id >> 4, c4 = (id & 15) << 2;
            float4 v = *reinterpret_cast<const float4*>(
                &pv[((size_t)bh * Pv + pt * 64 + p) * DHv + c4]);
            Tls[c4+0][p] = bf16_rn(v.x);
            Tls[c4+1][p] = bf16_rn(v.y);
            Tls[c4+2][p] = bf16_rn(v.z);
            Tls[c4+3][p] = bf16_rn(v.w);
        }
        __syncthreads();
        #pragma unroll
        for (int i = 0; i < 2; i++) {
            int id = i * 256 + tid;
            int d = id >> 3, u = id & 7;      // dh row, 8-key run index
            sh4 lo, hi;
            #pragma unroll
            for (int j = 0; j < 4; j++) {
                lo[j] = (short)Tls[d][u * 8 + j];
                hi[j] = (short)Tls[d][u * 8 + 4 + j];
            }
            int p0 = ((u >> 2) & 1) * 32 + (u & 1) * 16 + ((u >> 1) & 1) * 4;
            size_t base = ((size_t)bh * DHv + d) * Pv + pt * 64;
            *reinterpret_cast<sh4*>(&pvtb[base + p0])     = lo;
            *reinterpret_cast<sh4*>(&pvtb[base + p0 + 8]) = hi;
        }
    }
}

// ---------------------------------------------------------------------------
// Kernel 1: QKV projection.  NOW PIPELINED (flash round-10 pattern): 2-buffer
// LDS (64KB), counted vmcnt(8) -- next step's 8 gload16 stay in flight across
// the barrier; stage of step t+2 after the post-compute barrier (race-free).
// Q pre-scaled by 0.125*log2(e); V^T stored tau-permuted per 64-tile.
// ---------------------------------------------------------------------------
__global__ __launch_bounds__(256) void qkv_gemm(
    const unsigned short* __restrict__ xb,
    const unsigned short* __restrict__ wqb, const unsigned short* __restrict__ wkb,
    const unsigned short* __restrict__ wvb,
    unsigned short* __restrict__ qb, unsigned short* __restrict__ kb,
    unsigned short* __restrict__ vtb)
{
    __shared__ __align__(16) unsigned short As[2][128 * 64], Bs[2][128 * 64];
    const int tid = threadIdx.x;
    const int lane = tid & 63, w = tid >> 6;
    const int g = lane >> 4, tx = lane & 15;
    const int wr = w >> 1, wc = w & 1;
    const int m0 = blockIdx.x * 128, n0 = blockIdx.y * 128;
    const int z = blockIdx.z;
    const unsigned short* Wb = (z == 0) ? wqb : (z == 1) ? wkb : wvb;
    const int srow = lane >> 3, scol = lane & 7;

    f4 acc[4][4] = {};

    auto stage = [&](int buf, int step) {      // 8 gload16 per wave
        int k0 = step * 64;
        #pragma unroll
        for (int c = 0; c < 4; c++) {
            int row = w * 32 + c * 8 + srow;
            int su = (scol ^ (row & 7)) << 3;
            gload16(&xb[(size_t)(m0 + row) * Dv + k0 + su], &As[buf][(w * 32 + c * 8) * 64]);
            gload16(&Wb[(size_t)(n0 + row) * Dv + k0 + su], &Bs[buf][(w * 32 + c * 8) * 64]);
        }
    };
    auto compute = [&](int buf) {
        #pragma unroll
        for (int ks = 0; ks < 2; ks++) {
            sh8 fa[4], fb[4];
            #pragma unroll
            for (int mi = 0; mi < 4; mi++) {
                int r = wr * 64 + mi * 16 + tx;
                fa[mi] = *reinterpret_cast<const sh8*>(
                    &As[buf][(r * 64 + ks * 32 + g * 8) ^ ((r & 7) << 3)]);
            }
            #pragma unroll
            for (int ni = 0; ni < 4; ni++) {
                int r = wc * 64 + ni * 16 + tx;
                fb[ni] = *reinterpret_cast<const sh8*>(
                    &Bs[buf][(r * 64 + ks * 32 + g * 8) ^ ((r & 7) << 3)]);
            }
            if (z < 2) {
                #pragma unroll
                for (int mi = 0; mi < 4; mi++)
                    #pragma unroll
                    for (int ni = 0; ni < 4; ni++)
                        acc[mi][ni] = MFMA(fb[ni], fa[mi], acc[mi][ni]);   // C: row=n, col=m
            } else {
                #pragma unroll
                for (int mi = 0; mi < 4; mi++)
                    #pragma unroll
                    for (int ni = 0; ni < 4; ni++)
                        acc[mi][ni] = MFMA(fa[mi], fb[ni], acc[mi][ni]);   // C: row=m, col=n
            }
        }
    };

    stage(0, 0); stage(1, 1);                  // 16 loads in flight
    #pragma unroll 1
    for (int t = 0; t < 16; t++) {
        const int cur = t & 1;
        if (t < 15) asm volatile("s_waitcnt vmcnt(8)" ::: "memory");
        else        asm volatile("s_waitcnt vmcnt(0)" ::: "memory");
        __builtin_amdgcn_s_barrier();
        __builtin_amdgcn_sched_barrier(0);
        compute(cur);
        __builtin_amdgcn_sched_barrier(0);
        __builtin_amdgcn_s_barrier();          // all reads of cur done
        if (t + 2 < 16) stage(cur, t + 2);     // overwrite cur for step t+2
    }

    if (z < 2) {
        unsigned short* ob = (z == 0) ? qb : kb;
        const float sc = (z == 0) ? 0.1803368801f : 1.0f;   // 0.125*log2(e) into Q
        #pragma unroll
        for (int mi = 0; mi < 4; mi++)
            #pragma unroll
            for (int ni = 0; ni < 4; ni++) {
                int m = m0 + wr * 64 + mi * 16 + tx;          // col of C = x row
                int n = n0 + wc * 64 + ni * 16 + g * 4;       // row of C = W row (base)
                sh4 pkd;
                #pragma unroll
                for (int i = 0; i < 4; i++) pkd[i] = (short)bf16_rn(acc[mi][ni][i] * sc);
                *reinterpret_cast<sh4*>(&ob[(size_t)m * Dv + n]) = pkd;
            }
    } else {
        const int tb0 = ((m0 + wr * 64) & (Tv - 1));          // 64-aligned t-block
        const int b   = (m0 + wr * 64) >> 11;
        #pragma unroll
        for (int mi = 0; mi < 4; mi++)
            #pragma unroll
            for (int ni = 0; ni < 4; ni++) {
                // key = mi*16 + g*4 + i  ->  tau-slot = 32*(mi>>1) + 8g + 4*(mi&1) + i
                int t = tb0 + ((mi & 2) << 4) + (g << 3) + ((mi & 1) << 2);
                int n = n0 + wc * 64 + ni * 16 + tx;          // col of C = W row
                int h = n >> 6, dh = n & 63;
                sh4 pkd;
                #pragma unroll
                for (int i = 0; i < 4; i++) pkd[i] = (short)bf16_rn(acc[mi][ni][i]);
                *reinterpret_cast<sh4*>(&vtb[(((size_t)(b * Hv + h)) * DHv + dh) * Tv + t]) = pkd;
            }
    }
}

// ---------------------------------------------------------------------------
// Kernel 2: flash attention (round-12 structure, unchanged).  KEY-SPLIT +
// 3-buffer single-barrier pipeline, counted vmcnt, tau key-relabel keeps P
// in registers, no-max softmax, l via ones-MFMA.  LDS 50KB.
// ---------------------------------------------------------------------------
__global__ __launch_bounds__(256) void flash_mfma(
    const unsigned short* __restrict__ qbuf, const unsigned short* __restrict__ kb,
    const unsigned short* __restrict__ vtb,
    const unsigned short* __restrict__ pkb, const unsigned short* __restrict__ pvtb,
    unsigned short* __restrict__ yh)
{
    __shared__ __align__(16) unsigned short Ks[3][64 * 64], Vs[3][64 * 64];
    __shared__ float olex[2][4][64];
    const int tid = threadIdx.x;
    const int lane = tid & 63, w = tid >> 6;       // 4 waves
    const int kw = w & 1, qw = w >> 1;             // key-half, q-half
    const int g = lane >> 4, tx = lane & 15;
    // XCD swizzle: 512 blocks, 8 XCDs, chunk=64 => 4 bh per XCD
    const int pblk = blockIdx.x;
    const int L = (pblk & 7) * 64 + (pblk >> 3);
    const int qt = L & 15;                 // 16 q-tiles of 128 rows
    const int bh = L >> 4;
    const int b = bh >> 4, h = bh & 15;
    const int srow = lane >> 3, scol = lane & 7;

    // Q frags: 4 groups x 2 dh-halves (MFMA B-operand, pre-scaled)
    sh8 qf[4][2];
    #pragma unroll
    for (int qg = 0; qg < 4; qg++) {
        size_t base = ((size_t)(b * Tv) + qt * 128 + qw * 64 + qg * 16 + tx) * Dv + h * 64;
        qf[qg][0] = *reinterpret_cast<const sh8*>(&qbuf[base + g * 8]);
        qf[qg][1] = *reinterpret_cast<const sh8*>(&qbuf[base + 32 + g * 8]);
    }

    f4 o[4][4] = {};          // [q-group][dh-frag], partial over this wave's keys
    f4 ol[4] = {};            // ones-colsum accumulators (partial l per group)
    sh8 onesf;
    #pragma unroll
    for (int j = 0; j < 8; j++) onesf[j] = (short)0x3F80;   // bf16 1.0

    // staging pointers (wave stages rows w*16..+15 of both K and V tiles)
    const int r0 = w * 16 + srow, r1 = r0 + 8;
    const int su0 = (scol ^ (r0 & 7)) << 3;
    const int su1 = (scol ^ (r1 & 7)) << 3;
    const unsigned short* ka0 = &pkb[((size_t)bh * Pv + r0) * DHv + su0];
    const unsigned short* ka1 = &pkb[((size_t)bh * Pv + r1) * DHv + su1];
    const unsigned short* va0 = &pvtb[((size_t)bh * DHv + r0) * Pv + su0];
    const unsigned short* va1 = &pvtb[((size_t)bh * DHv + r1) * Pv + su1];

    auto stage = [&](int buf) {            // 4 gload16 per wave per tile
        gload16(ka0, &Ks[buf][(w * 16    ) * 64]);
        gload16(ka1, &Ks[buf][(w * 16 + 8) * 64]);
        gload16(va0, &Vs[buf][(w * 16    ) * 64]);
        gload16(va1, &Vs[buf][(w * 16 + 8) * 64]);
    };
    auto advance = [&](int nt) {           // nt = tile just staged
        if (nt == 7) {                     // switch prefix -> computed arrays
            ka0 = &kb[((size_t)(b * Tv) + r0) * Dv + h * 64 + su0];
            ka1 = &kb[((size_t)(b * Tv) + r1) * Dv + h * 64 + su1];
            va0 = &vtb[((size_t)bh * DHv + r0) * Tv + su0];
            va1 = &vtb[((size_t)bh * DHv + r1) * Tv + su1];
        } else if (nt < 7) { ka0 += 64 * DHv; ka1 += 64 * DHv; va0 += 64; va1 += 64; }
        else               { ka0 += 64 * Dv;  ka1 += 64 * Dv;  va0 += 64; va1 += 64; }
    };

    auto compute = [&](int cur) {
        sh8 kf[2][2], vf[4];
        #pragma unroll
        for (int nf = 0; nf < 2; nf++) {
            int rk = 32 * kw + nf * 16 + tx;
            kf[nf][0] = *reinterpret_cast<const sh8*>(
                &Ks[cur][(rk * 64 + g * 8) ^ ((rk & 7) << 3)]);
            kf[nf][1] = *reinterpret_cast<const sh8*>(
                &Ks[cur][(rk * 64 + 32 + g * 8) ^ ((rk & 7) << 3)]);
        }
        #pragma unroll
        for (int nf = 0; nf < 4; nf++) {
            int rv = nf * 16 + tx;
            vf[nf] = *reinterpret_cast<const sh8*>(
                &Vs[cur][(rv * 64 + 32 * kw + g * 8) ^ ((rv & 7) << 3)]);
        }
        #pragma unroll
        for (int qg = 0; qg < 4; qg++) {
            f4 sa = {}, sb = {};
            sa = MFMA(kf[0][0], qf[qg][0], sa); sa = MFMA(kf[0][1], qf[qg][1], sa);
            sb = MFMA(kf[1][0], qf[qg][0], sb); sb = MFMA(kf[1][1], qf[qg][1], sb);
            sh8 pf = packP(sa, sb);            // tau-slots 32kw + 8g + 4nf' + i
            #pragma unroll
            for (int nf = 0; nf < 4; nf++)
                o[qg][nf] = MFMA(vf[nf], pf, o[qg][nf]);
            ol[qg] = MFMA(onesf, pf, ol[qg]);
        }
    };

    stage(0); advance(0);
    stage(1); advance(1);                  // 8 loads in flight
    int cur = 0, stg = 2;

    #pragma unroll 1
    for (int t = 0; t < NT - 2; t++) {
        asm volatile("s_waitcnt vmcnt(4)" ::: "memory");   // tile t landed; t+1 flying
        __builtin_amdgcn_s_barrier();
        __builtin_amdgcn_sched_barrier(0);
        stage(stg); advance(t + 2);        // overwrite target: computed at t-1, safe
        compute(cur);
        __builtin_amdgcn_sched_barrier(0);
        cur = (cur == 2) ? 0 : cur + 1;
        stg = (stg == 2) ? 0 : stg + 1;
    }
    asm volatile("s_waitcnt vmcnt(4)" ::: "memory");       // tile NT-2 landed
    __builtin_amdgcn_s_barrier();
    __builtin_amdgcn_sched_barrier(0);
    compute(cur);
    __builtin_amdgcn_sched_barrier(0);
    cur = (cur == 2) ? 0 : cur + 1;
    asm volatile("s_waitcnt vmcnt(0)" ::: "memory");       // tile NT-1 landed
    __builtin_amdgcn_s_barrier();
    __builtin_amdgcn_sched_barrier(0);
    compute(cur);

    // cross-wave (kw) reduction: kw=1 writes partials to dead Ks/Vs, kw=0 adds
    float* ex = qw ? reinterpret_cast<float*>(Vs) : reinterpret_cast<float*>(Ks);
    if (kw) {
        #pragma unroll
        for (int qg = 0; qg < 4; qg++) {
            #pragma unroll
            for (int nf = 0; nf < 4; nf++)
                *reinterpret_cast<f4*>(&ex[((qg * 4 + nf) * 64 + lane) * 4]) = o[qg][nf];
            olex[qw][qg][lane] = ol[qg][0];
        }
    }
    __syncthreads();
    if (!kw) {
        #pragma unroll
        for (int qg = 0; qg < 4; qg++) {
            float l = ol[qg][0] + olex[qw][qg][lane];
            float inv = 1.0f / l;
            size_t ybase = ((size_t)(b * Tv) + qt * 128 + qw * 64 + qg * 16 + tx) * Dv + h * 64;
            #pragma unroll
            for (int nf = 0; nf < 4; nf++) {
                f4 op = o[qg][nf] +
                    *reinterpret_cast<const f4*>(&ex[((qg * 4 + nf) * 64 + lane) * 4]);
                sh4 ph;
                #pragma unroll
                for (int i = 0; i < 4; i++) ph[i] = (short)bf16_rn(op[i] * inv);
                *reinterpret_cast<sh4*>(&yh[ybase + nf * 16 + g * 4]) = ph;
            }
        }
    }
}

// ---------------------------------------------------------------------------
// Kernel 3: out = y @ Wo^T, fp32 out.  Single bf16 segment, K=1024 (16 steps).
// NOW PIPELINED: 2-buffer (48KB, free -- grid caps occupancy at 2/CU anyway),
// counted vmcnt(6).
// ---------------------------------------------------------------------------
__global__ __launch_bounds__(256) void out_gemm(
    const unsigned short* __restrict__ yh,
    const unsigned short* __restrict__ woh,
    float* __restrict__ out)
{
    __shared__ __align__(16) unsigned short As[2][64 * 64], Bs[2][128 * 64];
    const int tid = threadIdx.x;
    const int lane = tid & 63, w = tid >> 6;
    const int g = lane >> 4, tx = lane & 15;
    const int wr = w >> 1, wc = w & 1;
    const int m0 = blockIdx.x * 64, n0 = blockIdx.y * 128;
    const int srow = lane >> 3, scol = lane & 7;

    f4 acc[2][4] = {};

    auto stage = [&](int buf, int step) {      // 6 gload16 per wave
        int k0 = step * 64;
        #pragma unroll
        for (int c = 0; c < 2; c++) {
            int row = w * 16 + c * 8 + srow;
            int su = (scol ^ (row & 7)) << 3;
            gload16(&yh[(size_t)(m0 + row) * Dv + k0 + su], &As[buf][(w * 16 + c * 8) * 64]);
        }
        #pragma unroll
        for (int c = 0; c < 4; c++) {
            int row = w * 32 + c * 8 + srow;
            int su = (scol ^ (row & 7)) << 3;
            gload16(&woh[(size_t)(n0 + row) * Dv + k0 + su], &Bs[buf][(w * 32 + c * 8) * 64]);
        }
    };
    auto compute = [&](int buf) {
        #pragma unroll
        for (int ks = 0; ks < 2; ks++) {
            sh8 fa[2], fb[4];
            #pragma unroll
            for (int mi = 0; mi < 2; mi++) {
                int r = wr * 32 + mi * 16 + tx;
                fa[mi] = *reinterpret_cast<const sh8*>(
                    &As[buf][(r * 64 + ks * 32 + g * 8) ^ ((r & 7) << 3)]);
            }
            #pragma unroll
            for (int ni = 0; ni < 4; ni++) {
                int r = wc * 64 + ni * 16 + tx;
                fb[ni] = *reinterpret_cast<const sh8*>(
                    &Bs[buf][(r * 64 + ks * 32 + g * 8) ^ ((r & 7) << 3)]);
            }
            #pragma unroll
            for (int mi = 0; mi < 2; mi++)
                #pragma unroll
                for (int ni = 0; ni < 4; ni++)
                    acc[mi][ni] = MFMA(fb[ni], fa[mi], acc[mi][ni]);   // C: row=n, col=m
        }
    };

    stage(0, 0); stage(1, 1);                  // 12 loads in flight
    #pragma unroll 1
    for (int t = 0; t < 16; t++) {
        const int cur = t & 1;
        if (t < 15) asm volatile("s_waitcnt vmcnt(6)" ::: "memory");
        else        asm volatile("s_waitcnt vmcnt(0)" ::: "memory");
        __builtin_amdgcn_s_barrier();
        __builtin_amdgcn_sched_barrier(0);
        compute(cur);
        __builtin_amdgcn_sched_barrier(0);
        __builtin_amdgcn_s_barrier();
        if (t + 2 < 16) stage(cur, t + 2);
    }

    #pragma unroll
    for (int mi = 0; mi < 2; mi++)
        #pragma unroll
        for (int ni = 0; ni < 4; ni++) {
            int m = m0 + wr * 32 + mi * 16 + tx;
            int n = n0 + wc * 64 + ni * 16 + g * 4;
            *reinterpret_cast<float4*>(&out[(size_t)m * Dv + n]) =
                make_float4(acc[mi][ni][0], acc[mi][ni][1], acc[mi][ni][2], acc[mi][ni][3]);
        }
}

// ---------------------------------------------------------------------------
extern "C" void kernel_launch(void* const* d_in, const int* in_sizes, int n_in,
                              void* d_out, int out_size, void* d_ws, size_t ws_size,
                              hipStream_t stream)
{
    const float* x  = (const float*)d_in[0];
    const float* pk = (const float*)d_in[1];
    const float* pv = (const float*)d_in[2];
    const float* Wq = (const float*)d_in[3];
    const float* Wk = (const float*)d_in[4];
    const float* Wv = (const float*)d_in[5];
    const float* Wo = (const float*)d_in[6];

    const size_t M1 = 1048576;
    unsigned short* ws  = (unsigned short*)d_ws;   // 23M ushorts = 46 MB
    unsigned short* xb   = ws;                     // 4M  [B*T, D]
    unsigned short* wqb  = ws + 4  * M1;           // 1M
    unsigned short* wkb  = ws + 5  * M1;
    unsigned short* wvb  = ws + 6  * M1;
    unsigned short* woh  = ws + 7  * M1;
    unsigned short* pkb  = ws + 8  * M1;           // [B,H,P,DH]
    unsigned short* pvtb = ws + 9  * M1;           // [B,H,DH,P] tau-permuted keys
    unsigned short* qb   = ws + 10 * M1;           // 4M [B,T,D] (pre-scaled by C)
    unsigned short* kb   = ws + 14 * M1;           // 4M [B,T,D]
    unsigned short* vtb  = ws + 18 * M1;           // 4M [B,H,DH,T] tau-permuted keys
    unsigned short* yh   = ws + 22 * M1;           // 4M [B,T,D]

    prep_all<<<9472, 256, 0, stream>>>(x, Wq, Wk, Wv, pk, Wo, pv,
                                       xb, wqb, wkb, wvb, pkb, woh, pvtb);
    qkv_gemm<<<dim3(32, 8, 3), 256, 0, stream>>>(xb, wqb, wkb, wvb, qb, kb, vtb);
    flash_mfma<<<dim3(Bv * Hv * (Tv / 128)), 256, 0, stream>>>(qb, kb, vtb, pkb, pvtb, yh);
    out_gemm<<<dim3(64, 8), 256, 0, stream>>>(yh, woh, (float*)d_out);
}